// Round 2
// baseline (717.373 us; speedup 1.0000x reference)
//
#include <hip/hip_runtime.h>
#include <hip/hip_bf16.h>

// Decoupled RoPE MHA on MI355X (gfx950).
// B=2 S=2048 D=2048 H=16 dh=128 nope=64 rope=64
// Pipeline: cast->bf16, GEMM1 (QV), GEMM2 (K), rope/scatter, V-transpose,
//           flash attention (swapped QK^T, no LDS), GEMM3 (out proj).

typedef unsigned short u16;
typedef unsigned int u32;
typedef __bf16 bf16x8 __attribute__((ext_vector_type(8)));
typedef float f32x4 __attribute__((ext_vector_type(4)));

__device__ __forceinline__ u16 f2bf(float x) {
  union { __hip_bfloat16 h; u16 u; } c;
  c.h = __float2bfloat16(x);
  return c.u;
}
__device__ __forceinline__ float bf2f(u16 u) {
  union { u32 u; float f; } c;
  c.u = ((u32)u) << 16;
  return c.f;
}
__device__ __forceinline__ f32x4 mfma16(bf16x8 a, bf16x8 b, f32x4 c) {
  return __builtin_amdgcn_mfma_f32_16x16x32_bf16(a, b, c, 0, 0, 0);
}
__device__ __forceinline__ void gload_lds16(const void* g, void* l) {
  __builtin_amdgcn_global_load_lds((__attribute__((address_space(1))) void*)g,
                                   (__attribute__((address_space(3))) void*)l,
                                   16, 0, 0);
}

// ---------------- cast kernels ----------------
__global__ void cast4(const float4* __restrict__ src, u16* __restrict__ dst, int nv) {
  int i = blockIdx.x * blockDim.x + threadIdx.x;
  if (i >= nv) return;
  float4 v = src[i];
  u32 lo = (u32)f2bf(v.x) | ((u32)f2bf(v.y) << 16);
  u32 hi = (u32)f2bf(v.z) | ((u32)f2bf(v.w) << 16);
  ((uint2*)dst)[i] = make_uint2(lo, hi);
}

// wk is (1088, 2048); pad to (1152, 2048) with zeros so the GEMM tiles evenly.
__global__ void cast_wk_pad(const float* __restrict__ src, u16* __restrict__ dst) {
  int i = blockIdx.x * blockDim.x + threadIdx.x;  // over 1152*2048/4 = 589824
  int base = i * 4;
  int r = base >> 11;
  u32 lo = 0, hi = 0;
  if (r < 1088) {
    float4 v = ((const float4*)src)[i];
    lo = (u32)f2bf(v.x) | ((u32)f2bf(v.y) << 16);
    hi = (u32)f2bf(v.z) | ((u32)f2bf(v.w) << 16);
  }
  ((uint2*)dst)[i] = make_uint2(lo, hi);
}

// ---------------- GEMM: C[M,N] = A[M,K] @ W[N,K]^T (bf16 in, fp32 acc) -------
// m97 structure: 128x128 tile, BK=32, 4 waves (2x2 of 64x64), global_load_lds x16.
__device__ __forceinline__ void cstore(u16* C, size_t i, float v) { C[i] = f2bf(v); }
__device__ __forceinline__ void cstore(float* C, size_t i, float v) { C[i] = v; }

template <typename CT>
__global__ __launch_bounds__(256) void gemm_bt(const u16* __restrict__ A,
                                               const u16* __restrict__ W,
                                               CT* __restrict__ C,
                                               int M, int N, int K) {
  __shared__ u16 As[128 * 32];
  __shared__ u16 Bs[128 * 32];
  const int tid = threadIdx.x;
  const int wid = tid >> 6, lane = tid & 63;
  const int m0 = blockIdx.y * 128, n0 = blockIdx.x * 128;
  const int lr = lane & 15, lg = lane >> 4;
  const int wr = (wid >> 1) * 64, wc = (wid & 1) * 64;
  f32x4 acc[4][4] = {};

  // staging: thread t loads 16B chunks; linear LDS byte offset o = i*4096 + t*16
  // -> row = i*64 + t/4, col-chunk = (t&3)*8 elements.
  const u16* ga0 = A + (size_t)(m0 + (tid >> 2)) * K + (tid & 3) * 8;
  const u16* ga1 = ga0 + (size_t)64 * K;
  const u16* gb0 = W + (size_t)(n0 + (tid >> 2)) * K + (tid & 3) * 8;
  const u16* gb1 = gb0 + (size_t)64 * K;
  char* lA = (char*)As + wid * 1024;  // wave-uniform dest; HW adds lane*16
  char* lB = (char*)Bs + wid * 1024;

  for (int k0 = 0; k0 < K; k0 += 32) {
    gload_lds16(ga0 + k0, lA);
    gload_lds16(ga1 + k0, lA + 4096);
    gload_lds16(gb0 + k0, lB);
    gload_lds16(gb1 + k0, lB + 4096);
    asm volatile("s_waitcnt vmcnt(0)" ::: "memory");
    __syncthreads();
    bf16x8 af[4], bfr[4];
#pragma unroll
    for (int i = 0; i < 4; i++)
      af[i] = *(const bf16x8*)((const char*)As + ((wr + i * 16 + lr) * 32 + lg * 8) * 2);
#pragma unroll
    for (int j = 0; j < 4; j++)
      bfr[j] = *(const bf16x8*)((const char*)Bs + ((wc + j * 16 + lr) * 32 + lg * 8) * 2);
#pragma unroll
    for (int i = 0; i < 4; i++)
#pragma unroll
      for (int j = 0; j < 4; j++)
        acc[i][j] = mfma16(af[i], bfr[j], acc[i][j]);
    __syncthreads();
  }
  // C/D layout: col = lane&15, row = (lane>>4)*4 + reg
#pragma unroll
  for (int i = 0; i < 4; i++) {
    int row = m0 + wr + i * 16 + lg * 4;
#pragma unroll
    for (int j = 0; j < 4; j++) {
      int col = n0 + wc + j * 16 + lr;
#pragma unroll
      for (int r = 0; r < 4; r++)
        cstore(C, (size_t)(row + r) * N + col, acc[i][j][r]);
    }
  }
}

// ---------------- RoPE + scatter to (B,H,S,128) ----------------
// QV row layout: [Q (2048) | V (2048)], Q col = h*128+d. Kbuf row: 1152 cols,
// Kn = h*64+d (d<64), Kr = cols 1024..1087 (shared across heads).
__global__ __launch_bounds__(256) void rope_scatter(const u16* __restrict__ QV,
                                                    const u16* __restrict__ Kbuf,
                                                    u16* __restrict__ qh,
                                                    u16* __restrict__ kh,
                                                    float* __restrict__ k_out, int S) {
  const int row = blockIdx.x;  // b*S + s
  const int b = row / S, s = row - b * S;
  const int tid = threadIdx.x;
  __shared__ float kr[64];
  const float LOG1E4_64 = 0.14391156511f;  // ln(10000)/64
  if (tid < 32) {
    int i = tid;
    float freq = __expf(-(float)i * LOG1E4_64);
    float ang = (float)s * freq;
    float sn, c;
    __sincosf(ang, &sn, &c);
    float a = bf2f(Kbuf[(size_t)row * 1152 + 1024 + i]);
    float bb = bf2f(Kbuf[(size_t)row * 1152 + 1024 + 32 + i]);
    kr[i] = a * c - bb * sn;
    kr[i + 32] = bb * c + a * sn;
  }
  __syncthreads();
  // q_heads: rope applied to d in [64,128)
  for (int idx = tid; idx < 2048; idx += 256) {
    int h = idx >> 7, d = idx & 127;
    float val;
    if (d < 64) {
      val = bf2f(QV[(size_t)row * 4096 + h * 128 + d]);
    } else {
      int j = d - 64, jj = j & 31;
      float freq = __expf(-(float)jj * LOG1E4_64);
      float sn, c;
      __sincosf((float)s * freq, &sn, &c);
      float x1 = bf2f(QV[(size_t)row * 4096 + h * 128 + 64 + jj]);
      float x2 = bf2f(QV[(size_t)row * 4096 + h * 128 + 96 + jj]);
      val = (j < 32) ? (x1 * c - x2 * sn) : (x2 * c + x1 * sn);
    }
    qh[((size_t)(b * 16 + h) * S + s) * 128 + d] = f2bf(val);
  }
  // k_heads: Kn + broadcast rope'd Kr; also fp32 output
  for (int idx = tid; idx < 2048; idx += 256) {
    int h = idx >> 7, d = idx & 127;
    float val = (d < 64) ? bf2f(Kbuf[(size_t)row * 1152 + h * 64 + d]) : kr[d - 64];
    size_t o = ((size_t)(b * 16 + h) * S + s) * 128 + d;
    kh[o] = f2bf(val);
    k_out[o] = val;
  }
}

// ---------------- V: write v_heads fp32 + transposed Vt (B,H,128,S) ----------
__global__ __launch_bounds__(256) void v_scatter(const u16* __restrict__ QV,
                                                 u16* __restrict__ vt,
                                                 float* __restrict__ v_out, int S) {
  const int blk = blockIdx.x;
  const int st = blk & 63;         // S/32
  const int dt = (blk >> 6) & 3;   // 128/32
  const int bh = blk >> 8;
  const int b = bh >> 4, h = bh & 15;
  __shared__ u16 t[32][34];
  const int tx = threadIdx.x & 31, ty = threadIdx.x >> 5;
  const int s0 = st * 32, d0 = dt * 32;
#pragma unroll
  for (int i = 0; i < 4; i++) {
    int sl = ty + 8 * i;
    u16 u = QV[(size_t)(b * S + s0 + sl) * 4096 + 2048 + h * 128 + d0 + tx];
    t[sl][tx] = u;
    v_out[((size_t)bh * S + s0 + sl) * 128 + d0 + tx] = bf2f(u);
  }
  __syncthreads();
#pragma unroll
  for (int i = 0; i < 4; i++) {
    int dl = ty + 8 * i;
    vt[((size_t)bh * 128 + d0 + dl) * S + s0 + tx] = t[tx][dl];
  }
}

// ---------------- flash attention (causal) ----------------
// 4 waves/block, each wave owns 16 q rows. Swapped QK^T: S^T = mfma(K, Q)
// -> lane holds col q = lane&15, keys (lane>>4)*4+reg. P redistributed via
// shfl into A-frag layout (row q = lane&15, k = (lane>>4)*8+j).
__global__ __launch_bounds__(256) void flash_attn(const u16* __restrict__ Qh,
                                                  const u16* __restrict__ Kh,
                                                  const u16* __restrict__ Vt,
                                                  u16* __restrict__ attn, int S) {
  const int tid = threadIdx.x, wid = tid >> 6, lane = tid & 63;
  const int qblocks = S >> 6;
  const int bh = blockIdx.x / qblocks;
  const int q0 = (blockIdx.x % qblocks) * 64 + wid * 16;
  const int b = bh >> 4, h = bh & 15;
  const int q = lane & 15, g = lane >> 4;
  const u16* Qb = Qh + (size_t)bh * S * 128;
  const u16* Kb = Kh + (size_t)bh * S * 128;
  const u16* Vb = Vt + (size_t)bh * 128 * S;
  const int qg = q0 + q;

  bf16x8 qf[4];
#pragma unroll
  for (int f = 0; f < 4; f++)
    qf[f] = *(const bf16x8*)(Qb + (size_t)qg * 128 + f * 32 + g * 8);

  f32x4 acc[8] = {};
  float m = -INFINITY, l = 0.f;
  const float sc = 0.08838834764831845f;  // 1/sqrt(128)
  const int ktiles = (q0 >> 5) + 1;

  for (int kt = 0; kt < ktiles; ++kt) {
    const int kb = kt << 5;
    f32x4 s0 = {0.f, 0.f, 0.f, 0.f}, s1 = {0.f, 0.f, 0.f, 0.f};
#pragma unroll
    for (int f = 0; f < 4; f++) {
      bf16x8 k0 = *(const bf16x8*)(Kb + (size_t)(kb + q) * 128 + f * 32 + g * 8);
      bf16x8 k1 = *(const bf16x8*)(Kb + (size_t)(kb + 16 + q) * 128 + f * 32 + g * 8);
      s0 = mfma16(k0, qf[f], s0);
      s1 = mfma16(k1, qf[f], s1);
    }
    float v[8];
    const bool maskt = (kb + 31 > q0);
#pragma unroll
    for (int r = 0; r < 4; r++) {
      int key0 = kb + g * 4 + r;
      v[r] = s0[r] * sc;
      v[4 + r] = s1[r] * sc;
      if (maskt) {
        if (key0 > qg) v[r] = -1e30f;
        if (key0 + 16 > qg) v[4 + r] = -1e30f;
      }
    }
    float tm = v[0];
#pragma unroll
    for (int i = 1; i < 8; i++) tm = fmaxf(tm, v[i]);
    tm = fmaxf(tm, __shfl_xor(tm, 16));
    tm = fmaxf(tm, __shfl_xor(tm, 32));
    float mnew = fmaxf(m, tm);
    float corr = __expf(m - mnew);
    float p[8];
    float ts = 0.f;
#pragma unroll
    for (int i = 0; i < 8; i++) {
      p[i] = __expf(v[i] - mnew);
      ts += p[i];
    }
    ts += __shfl_xor(ts, 16);
    ts += __shfl_xor(ts, 32);
    l = l * corr + ts;
    m = mnew;
    // rescale O: O rows are q-rows g*4+r; fetch corr of that q from a lane with lane&15==g*4+r
    float corr_r[4];
#pragma unroll
    for (int r = 0; r < 4; r++)
      corr_r[r] = __shfl(corr, (lane & 48) | (g * 4 + r));
#pragma unroll
    for (int j = 0; j < 8; j++)
#pragma unroll
      for (int r = 0; r < 4; r++) acc[j][r] *= corr_r[r];
    // pack P to bf16 and redistribute into A-frag layout.
    // dst lane (g,q) needs keys [g*8, g*8+8) of query q:
    //   keys 0..15 live as p[0..3] (w0) on src lanes g' = key>>2;
    //   keys 16..31 live as p[4..7] (w1) on src lanes g' = (key-16)>>2.
    // src lanes: src0 = (q | (g&1)<<5) -> g' = (g&1)*2, and src0+16 -> g'+1.
    // The w0/w1 half is chosen by DST (g&2) - must shuffle both and select here.
    u32 w0a = (u32)f2bf(p[0]) | ((u32)f2bf(p[1]) << 16);
    u32 w0b = (u32)f2bf(p[2]) | ((u32)f2bf(p[3]) << 16);
    u32 w1a = (u32)f2bf(p[4]) | ((u32)f2bf(p[5]) << 16);
    u32 w1b = (u32)f2bf(p[6]) | ((u32)f2bf(p[7]) << 16);
    int src0 = q | ((g & 1) << 5);
    u32 a_lo  = (u32)__shfl((int)w0a, src0);
    u32 b_lo  = (u32)__shfl((int)w0b, src0);
    u32 a_lo2 = (u32)__shfl((int)w0a, src0 + 16);
    u32 b_lo2 = (u32)__shfl((int)w0b, src0 + 16);
    u32 a_hi  = (u32)__shfl((int)w1a, src0);
    u32 b_hi  = (u32)__shfl((int)w1b, src0);
    u32 a_hi2 = (u32)__shfl((int)w1a, src0 + 16);
    u32 b_hi2 = (u32)__shfl((int)w1b, src0 + 16);
    const bool hi = (g & 2);
    union { u32 u[4]; bf16x8 v; } pc;
    pc.u[0] = hi ? a_hi : a_lo;
    pc.u[1] = hi ? b_hi : b_lo;
    pc.u[2] = hi ? a_hi2 : a_lo2;
    pc.u[3] = hi ? b_hi2 : b_lo2;
#pragma unroll
    for (int j = 0; j < 8; j++) {
      bf16x8 vf = *(const bf16x8*)(Vb + (size_t)(j * 16 + q) * S + kb + g * 8);
      acc[j] = mfma16(pc.v, vf, acc[j]);
    }
  }
  float linv = 1.0f / l;
  float linv_r[4];
#pragma unroll
  for (int r = 0; r < 4; r++)
    linv_r[r] = __shfl(linv, (lane & 48) | (g * 4 + r));
  u16* ab = attn + (size_t)(b * S + q0) * 2048 + h * 128;
#pragma unroll
  for (int j = 0; j < 8; j++)
#pragma unroll
    for (int r = 0; r < 4; r++)
      ab[(size_t)(g * 4 + r) * 2048 + j * 16 + q] = f2bf(acc[j][r] * linv_r[r]);
}

// ---------------- launch ----------------
extern "C" void kernel_launch(void* const* d_in, const int* in_sizes, int n_in,
                              void* d_out, int out_size, void* d_ws, size_t ws_size,
                              hipStream_t stream) {
  (void)in_sizes; (void)n_in; (void)out_size; (void)ws_size;
  const int S = 2048;
  const float* x = (const float*)d_in[0];
  const float* qkv = (const float*)d_in[1];
  const float* wk = (const float*)d_in[2];
  const float* wo = (const float*)d_in[3];
  float* out = (float*)d_out;
  float* k_out = out + (size_t)8388608;
  float* v_out = out + (size_t)16777216;

  char* ws = (char*)d_ws;
  // workspace layout (123.2 MB total); attn aliases x_bf, k aliases qkv_bf
  u16* x_bf   = (u16*)(ws + 0);           // 16.78 MB (later: attn_bf)
  u16* qkv_bf = (u16*)(ws + 16777216);    // 16.78 MB (later: k_bf)
  u16* wk_bf  = (u16*)(ws + 33554432);    // 4.72 MB (padded 1152x2048)
  u16* wo_bf  = (u16*)(ws + 38273024);    // 8.39 MB
  u16* qv_bf  = (u16*)(ws + 46661632);    // 33.55 MB (4096x4096)
  u16* kbuf   = (u16*)(ws + 80216064);    // 9.44 MB (4096x1152)
  u16* q_bf   = (u16*)(ws + 89653248);    // 16.78 MB (B,H,S,128)
  u16* vt_bf  = (u16*)(ws + 106430464);   // 16.78 MB (B,H,128,S)
  u16* attn_bf = x_bf;
  u16* k_bf = qkv_bf;

  cast4<<<8192, 256, 0, stream>>>((const float4*)x, x_bf, 2097152);
  cast4<<<8192, 256, 0, stream>>>((const float4*)qkv, qkv_bf, 2097152);
  cast4<<<4096, 256, 0, stream>>>((const float4*)wo, wo_bf, 1048576);
  cast_wk_pad<<<2304, 256, 0, stream>>>(wk, wk_bf);

  gemm_bt<u16><<<dim3(32, 32), 256, 0, stream>>>(x_bf, qkv_bf, qv_bf, 4096, 4096, 2048);
  gemm_bt<u16><<<dim3(9, 32), 256, 0, stream>>>(x_bf, wk_bf, kbuf, 4096, 1152, 2048);
  rope_scatter<<<4096, 256, 0, stream>>>(qv_bf, kbuf, q_bf, k_bf, k_out, S);
  v_scatter<<<8192, 256, 0, stream>>>(qv_bf, vt_bf, v_out, S);
  flash_attn<<<1024, 256, 0, stream>>>(q_bf, k_bf, vt_bf, attn_bf, S);
  gemm_bt<float><<<dim3(16, 32), 256, 0, stream>>>(attn_bf, wo_bf, out, 4096, 2048, 2048);
}

// Round 3
// 377.978 us; speedup vs baseline: 1.8979x; 1.8979x over previous
//
#include <hip/hip_runtime.h>
#include <hip/hip_bf16.h>

// Decoupled RoPE MHA on MI355X (gfx950).
// B=2 S=2048 D=2048 H=16 dh=128 nope=64 rope=64
// R3: flash attention rebuilt with LDS-staged double-buffered 64-key K/V
// tiles (pre-swizzled global source -> linear LDS, XOR-swizzled ds_read).

typedef unsigned short u16;
typedef unsigned int u32;
typedef __bf16 bf16x8 __attribute__((ext_vector_type(8)));
typedef float f32x4 __attribute__((ext_vector_type(4)));

__device__ __forceinline__ u16 f2bf(float x) {
  union { __hip_bfloat16 h; u16 u; } c;
  c.h = __float2bfloat16(x);
  return c.u;
}
__device__ __forceinline__ float bf2f(u16 u) {
  union { u32 u; float f; } c;
  c.u = ((u32)u) << 16;
  return c.f;
}
__device__ __forceinline__ f32x4 mfma16(bf16x8 a, bf16x8 b, f32x4 c) {
  return __builtin_amdgcn_mfma_f32_16x16x32_bf16(a, b, c, 0, 0, 0);
}
__device__ __forceinline__ void gload_lds16(const void* g, void* l) {
  __builtin_amdgcn_global_load_lds((__attribute__((address_space(1))) void*)g,
                                   (__attribute__((address_space(3))) void*)l,
                                   16, 0, 0);
}

// ---------------- cast kernels ----------------
__global__ void cast4(const float4* __restrict__ src, u16* __restrict__ dst, int nv) {
  int i = blockIdx.x * blockDim.x + threadIdx.x;
  if (i >= nv) return;
  float4 v = src[i];
  u32 lo = (u32)f2bf(v.x) | ((u32)f2bf(v.y) << 16);
  u32 hi = (u32)f2bf(v.z) | ((u32)f2bf(v.w) << 16);
  ((uint2*)dst)[i] = make_uint2(lo, hi);
}

// wk is (1088, 2048); pad to (1152, 2048) with zeros so the GEMM tiles evenly.
__global__ void cast_wk_pad(const float* __restrict__ src, u16* __restrict__ dst) {
  int i = blockIdx.x * blockDim.x + threadIdx.x;  // over 1152*2048/4 = 589824
  int base = i * 4;
  int r = base >> 11;
  u32 lo = 0, hi = 0;
  if (r < 1088) {
    float4 v = ((const float4*)src)[i];
    lo = (u32)f2bf(v.x) | ((u32)f2bf(v.y) << 16);
    hi = (u32)f2bf(v.z) | ((u32)f2bf(v.w) << 16);
  }
  ((uint2*)dst)[i] = make_uint2(lo, hi);
}

// ---------------- GEMM: C[M,N] = A[M,K] @ W[N,K]^T (bf16 in, fp32 acc) -------
__device__ __forceinline__ void cstore(u16* C, size_t i, float v) { C[i] = f2bf(v); }
__device__ __forceinline__ void cstore(float* C, size_t i, float v) { C[i] = v; }

template <typename CT>
__global__ __launch_bounds__(256) void gemm_bt(const u16* __restrict__ A,
                                               const u16* __restrict__ W,
                                               CT* __restrict__ C,
                                               int M, int N, int K) {
  __shared__ u16 As[128 * 32];
  __shared__ u16 Bs[128 * 32];
  const int tid = threadIdx.x;
  const int wid = tid >> 6, lane = tid & 63;
  const int m0 = blockIdx.y * 128, n0 = blockIdx.x * 128;
  const int lr = lane & 15, lg = lane >> 4;
  const int wr = (wid >> 1) * 64, wc = (wid & 1) * 64;
  f32x4 acc[4][4] = {};

  const u16* ga0 = A + (size_t)(m0 + (tid >> 2)) * K + (tid & 3) * 8;
  const u16* ga1 = ga0 + (size_t)64 * K;
  const u16* gb0 = W + (size_t)(n0 + (tid >> 2)) * K + (tid & 3) * 8;
  const u16* gb1 = gb0 + (size_t)64 * K;
  char* lA = (char*)As + wid * 1024;
  char* lB = (char*)Bs + wid * 1024;

  for (int k0 = 0; k0 < K; k0 += 32) {
    gload_lds16(ga0 + k0, lA);
    gload_lds16(ga1 + k0, lA + 4096);
    gload_lds16(gb0 + k0, lB);
    gload_lds16(gb1 + k0, lB + 4096);
    asm volatile("s_waitcnt vmcnt(0)" ::: "memory");
    __syncthreads();
    bf16x8 af[4], bfr[4];
#pragma unroll
    for (int i = 0; i < 4; i++)
      af[i] = *(const bf16x8*)((const char*)As + ((wr + i * 16 + lr) * 32 + lg * 8) * 2);
#pragma unroll
    for (int j = 0; j < 4; j++)
      bfr[j] = *(const bf16x8*)((const char*)Bs + ((wc + j * 16 + lr) * 32 + lg * 8) * 2);
#pragma unroll
    for (int i = 0; i < 4; i++)
#pragma unroll
      for (int j = 0; j < 4; j++)
        acc[i][j] = mfma16(af[i], bfr[j], acc[i][j]);
    __syncthreads();
  }
#pragma unroll
  for (int i = 0; i < 4; i++) {
    int row = m0 + wr + i * 16 + lg * 4;
#pragma unroll
    for (int j = 0; j < 4; j++) {
      int col = n0 + wc + j * 16 + lr;
#pragma unroll
      for (int r = 0; r < 4; r++)
        cstore(C, (size_t)(row + r) * N + col, acc[i][j][r]);
    }
  }
}

// ---------------- RoPE + scatter to (B,H,S,128) ----------------
__global__ __launch_bounds__(256) void rope_scatter(const u16* __restrict__ QV,
                                                    const u16* __restrict__ Kbuf,
                                                    u16* __restrict__ qh,
                                                    u16* __restrict__ kh,
                                                    float* __restrict__ k_out, int S) {
  const int row = blockIdx.x;  // b*S + s
  const int b = row / S, s = row - b * S;
  const int tid = threadIdx.x;
  __shared__ float kr[64];
  const float LOG1E4_64 = 0.14391156511f;  // ln(10000)/64
  if (tid < 32) {
    int i = tid;
    float freq = __expf(-(float)i * LOG1E4_64);
    float ang = (float)s * freq;
    float sn, c;
    __sincosf(ang, &sn, &c);
    float a = bf2f(Kbuf[(size_t)row * 1152 + 1024 + i]);
    float bb = bf2f(Kbuf[(size_t)row * 1152 + 1024 + 32 + i]);
    kr[i] = a * c - bb * sn;
    kr[i + 32] = bb * c + a * sn;
  }
  __syncthreads();
  for (int idx = tid; idx < 2048; idx += 256) {
    int h = idx >> 7, d = idx & 127;
    float val;
    if (d < 64) {
      val = bf2f(QV[(size_t)row * 4096 + h * 128 + d]);
    } else {
      int j = d - 64, jj = j & 31;
      float freq = __expf(-(float)jj * LOG1E4_64);
      float sn, c;
      __sincosf((float)s * freq, &sn, &c);
      float x1 = bf2f(QV[(size_t)row * 4096 + h * 128 + 64 + jj]);
      float x2 = bf2f(QV[(size_t)row * 4096 + h * 128 + 96 + jj]);
      val = (j < 32) ? (x1 * c - x2 * sn) : (x2 * c + x1 * sn);
    }
    qh[((size_t)(b * 16 + h) * S + s) * 128 + d] = f2bf(val);
  }
  for (int idx = tid; idx < 2048; idx += 256) {
    int h = idx >> 7, d = idx & 127;
    float val = (d < 64) ? bf2f(Kbuf[(size_t)row * 1152 + h * 64 + d]) : kr[d - 64];
    size_t o = ((size_t)(b * 16 + h) * S + s) * 128 + d;
    kh[o] = f2bf(val);
    k_out[o] = val;
  }
}

// ---------------- V: write v_heads fp32 + transposed Vt (B,H,128,S) ----------
__global__ __launch_bounds__(256) void v_scatter(const u16* __restrict__ QV,
                                                 u16* __restrict__ vt,
                                                 float* __restrict__ v_out, int S) {
  const int blk = blockIdx.x;
  const int st = blk & 63;
  const int dt = (blk >> 6) & 3;
  const int bh = blk >> 8;
  const int b = bh >> 4, h = bh & 15;
  __shared__ u16 t[32][34];
  const int tx = threadIdx.x & 31, ty = threadIdx.x >> 5;
  const int s0 = st * 32, d0 = dt * 32;
#pragma unroll
  for (int i = 0; i < 4; i++) {
    int sl = ty + 8 * i;
    u16 u = QV[(size_t)(b * S + s0 + sl) * 4096 + 2048 + h * 128 + d0 + tx];
    t[sl][tx] = u;
    v_out[((size_t)bh * S + s0 + sl) * 128 + d0 + tx] = bf2f(u);
  }
  __syncthreads();
#pragma unroll
  for (int i = 0; i < 4; i++) {
    int dl = ty + 8 * i;
    vt[((size_t)bh * 128 + d0 + dl) * S + s0 + tx] = t[tx][dl];
  }
}

// ---------------- flash attention v2 (causal, LDS-staged K/V) ----------------
// 4 waves/block, wave owns 16 q rows; block spans 64 q rows. K/V staged in
// LDS as 64-key double-buffered tiles via global_load_lds with PRE-SWIZZLED
// global source (LDS linear, logical layout byte^=((row&7)<<4) kills the
// 16/32-way bank conflicts on the 256B/128B-stride fragment reads).
// LDS map: [0,16K) Kbuf0 | [16K,32K) Kbuf1 | [32K,48K) Vbuf0 | [48K,64K) Vbuf1
// K tile: [64 rows][128 cols] bf16 (256 B/row). V tile: [128 d][64 keys] (128 B/row).
__global__ __launch_bounds__(256) void flash_attn2(const u16* __restrict__ Qh,
                                                   const u16* __restrict__ Kh,
                                                   const u16* __restrict__ Vt,
                                                   u16* __restrict__ attn, int S) {
  __shared__ char lds[65536];
  const int tid = threadIdx.x, wid = tid >> 6, lane = tid & 63;
  // longest q-blocks first (qb descending) to reduce causal tail
  const int bh = blockIdx.x & 31;
  const int qb = 31 - (int)(blockIdx.x >> 5);
  const int q0 = qb * 64 + wid * 16;
  const int b = bh >> 4, h = bh & 15;
  const int q = lane & 15, g = lane >> 4;
  const u16* Qb = Qh + (size_t)bh * S * 128;
  const u16* Kb = Kh + (size_t)bh * S * 128;
  const u16* Vb = Vt + (size_t)bh * 128 * S;
  const int qg = q0 + q;
  const int xr = (q & 7) << 4;  // read-side XOR swizzle (row&7)<<4; all frag rows = q mod 8

  // per-lane pre-swizzled stage sources (inverse of the read swizzle)
  const u16* srcK[4];
  const u16* srcV[4];
#pragma unroll
  for (int i = 0; i < 4; i++) {
    int o = ((i * 4 + wid) << 10) | (lane << 4);  // linear LDS byte slot
    int rK = o >> 8, cbK = (o & 255) ^ ((rK & 7) << 4);
    srcK[i] = Kb + rK * 128 + (cbK >> 1);
    int dV = o >> 7, kbV = (o & 127) ^ ((dV & 7) << 4);
    srcV[i] = Vb + (size_t)dV * S + (kbV >> 1);
  }

  bf16x8 qf[4];
#pragma unroll
  for (int f = 0; f < 4; f++)
    qf[f] = *(const bf16x8*)(Qb + (size_t)qg * 128 + f * 32 + g * 8);

  f32x4 acc[8] = {};
  float m = -INFINITY, l = 0.f;
  const float sc = 0.08838834764831845f;  // 1/sqrt(128)
  const int ktiles = qb + 1;

  // prologue: stage tile 0 into buf 0
#pragma unroll
  for (int i = 0; i < 4; i++) {
    char* ld = lds + ((i * 4 + wid) << 10);
    gload_lds16(srcK[i], ld);
    gload_lds16(srcV[i], ld + 32768);
  }
  asm volatile("s_waitcnt vmcnt(0)" ::: "memory");
  __syncthreads();

  int buf = 0;
  for (int kt = 0; kt < ktiles; ++kt) {
    if (kt + 1 < ktiles) {
      const int nb = buf ^ 1;
      const int adv = (kt + 1) * 8192;   // K: 64 rows * 128
      const int advv = (kt + 1) * 64;    // V: 64 keys
#pragma unroll
      for (int i = 0; i < 4; i++) {
        char* ld = lds + nb * 16384 + ((i * 4 + wid) << 10);
        gload_lds16(srcK[i] + adv, ld);
        gload_lds16(srcV[i] + advv, ld + 32768);
      }
    }
    const char* Kt = lds + buf * 16384;
    const char* Vl = lds + 32768 + buf * 16384;

#pragma unroll
    for (int sub = 0; sub < 2; ++sub) {
      const int kb2 = sub * 32;
      const int kbg = kt * 64 + kb2;       // global key base of subtile
      if (kbg > q0 + 15) break;            // wave-uniform: fully masked
      f32x4 s0 = {0.f, 0.f, 0.f, 0.f}, s1 = {0.f, 0.f, 0.f, 0.f};
      const char* Kq = Kt + (kb2 + q) * 256;
#pragma unroll
      for (int f = 0; f < 4; f++) {
        bf16x8 k0 = *(const bf16x8*)(Kq + ((f * 64 + g * 16) ^ xr));
        bf16x8 k1 = *(const bf16x8*)(Kq + 4096 + ((f * 64 + g * 16) ^ xr));
        s0 = mfma16(k0, qf[f], s0);
        s1 = mfma16(k1, qf[f], s1);
      }
      float v[8];
      const bool maskt = (kbg + 31 > q0);
#pragma unroll
      for (int r = 0; r < 4; r++) {
        int key0 = kbg + g * 4 + r;
        v[r] = s0[r] * sc;
        v[4 + r] = s1[r] * sc;
        if (maskt) {
          if (key0 > qg) v[r] = -1e30f;
          if (key0 + 16 > qg) v[4 + r] = -1e30f;
        }
      }
      float tm = v[0];
#pragma unroll
      for (int i = 1; i < 8; i++) tm = fmaxf(tm, v[i]);
      tm = fmaxf(tm, __shfl_xor(tm, 16));
      tm = fmaxf(tm, __shfl_xor(tm, 32));
      float mnew = fmaxf(m, tm);
      float corr = __expf(m - mnew);
      float p[8];
      float ts = 0.f;
#pragma unroll
      for (int i = 0; i < 8; i++) {
        p[i] = __expf(v[i] - mnew);
        ts += p[i];
      }
      ts += __shfl_xor(ts, 16);
      ts += __shfl_xor(ts, 32);
      l = l * corr + ts;
      m = mnew;
      float corr_r[4];
#pragma unroll
      for (int r = 0; r < 4; r++)
        corr_r[r] = __shfl(corr, (lane & 48) | (g * 4 + r));
#pragma unroll
      for (int j = 0; j < 8; j++)
#pragma unroll
        for (int r = 0; r < 4; r++) acc[j][r] *= corr_r[r];
      // P redistribution (verified): dst lane (g,q) needs keys [g*8,g*8+8) of
      // query q; shuffle both halves, select by dst (g&2).
      u32 w0a = (u32)f2bf(p[0]) | ((u32)f2bf(p[1]) << 16);
      u32 w0b = (u32)f2bf(p[2]) | ((u32)f2bf(p[3]) << 16);
      u32 w1a = (u32)f2bf(p[4]) | ((u32)f2bf(p[5]) << 16);
      u32 w1b = (u32)f2bf(p[6]) | ((u32)f2bf(p[7]) << 16);
      int src0 = q | ((g & 1) << 5);
      u32 a_lo  = (u32)__shfl((int)w0a, src0);
      u32 b_lo  = (u32)__shfl((int)w0b, src0);
      u32 a_lo2 = (u32)__shfl((int)w0a, src0 + 16);
      u32 b_lo2 = (u32)__shfl((int)w0b, src0 + 16);
      u32 a_hi  = (u32)__shfl((int)w1a, src0);
      u32 b_hi  = (u32)__shfl((int)w1b, src0);
      u32 a_hi2 = (u32)__shfl((int)w1a, src0 + 16);
      u32 b_hi2 = (u32)__shfl((int)w1b, src0 + 16);
      const bool hi = (g & 2);
      union { u32 u[4]; bf16x8 v; } pc;
      pc.u[0] = hi ? a_hi : a_lo;
      pc.u[1] = hi ? b_hi : b_lo;
      pc.u[2] = hi ? a_hi2 : a_lo2;
      pc.u[3] = hi ? b_hi2 : b_lo2;
      const int vcol = (sub * 64 + g * 16) ^ xr;
#pragma unroll
      for (int j = 0; j < 8; j++) {
        bf16x8 vf = *(const bf16x8*)(Vl + (j * 16 + q) * 128 + vcol);
        acc[j] = mfma16(pc.v, vf, acc[j]);
      }
    }
    asm volatile("s_waitcnt vmcnt(0)" ::: "memory");
    __syncthreads();
    buf ^= 1;
  }

  float linv = 1.0f / l;
  float linv_r[4];
#pragma unroll
  for (int r = 0; r < 4; r++)
    linv_r[r] = __shfl(linv, (lane & 48) | (g * 4 + r));
  u16* ab = attn + (size_t)(b * S + q0) * 2048 + h * 128;
#pragma unroll
  for (int j = 0; j < 8; j++)
#pragma unroll
    for (int r = 0; r < 4; r++)
      ab[(size_t)(g * 4 + r) * 2048 + j * 16 + q] = f2bf(acc[j][r] * linv_r[r]);
}

// ---------------- launch ----------------
extern "C" void kernel_launch(void* const* d_in, const int* in_sizes, int n_in,
                              void* d_out, int out_size, void* d_ws, size_t ws_size,
                              hipStream_t stream) {
  (void)in_sizes; (void)n_in; (void)out_size; (void)ws_size;
  const int S = 2048;
  const float* x = (const float*)d_in[0];
  const float* qkv = (const float*)d_in[1];
  const float* wk = (const float*)d_in[2];
  const float* wo = (const float*)d_in[3];
  float* out = (float*)d_out;
  float* k_out = out + (size_t)8388608;
  float* v_out = out + (size_t)16777216;

  char* ws = (char*)d_ws;
  u16* x_bf   = (u16*)(ws + 0);           // 16.78 MB (later: attn_bf)
  u16* qkv_bf = (u16*)(ws + 16777216);    // 16.78 MB (later: k_bf)
  u16* wk_bf  = (u16*)(ws + 33554432);    // 4.72 MB (padded 1152x2048)
  u16* wo_bf  = (u16*)(ws + 38273024);    // 8.39 MB
  u16* qv_bf  = (u16*)(ws + 46661632);    // 33.55 MB (4096x4096)
  u16* kbuf   = (u16*)(ws + 80216064);    // 9.44 MB (4096x1152)
  u16* q_bf   = (u16*)(ws + 89653248);    // 16.78 MB (B,H,S,128)
  u16* vt_bf  = (u16*)(ws + 106430464);   // 16.78 MB (B,H,128,S)
  u16* attn_bf = x_bf;
  u16* k_bf = qkv_bf;

  cast4<<<8192, 256, 0, stream>>>((const float4*)x, x_bf, 2097152);
  cast4<<<8192, 256, 0, stream>>>((const float4*)qkv, qkv_bf, 2097152);
  cast4<<<4096, 256, 0, stream>>>((const float4*)wo, wo_bf, 1048576);
  cast_wk_pad<<<2304, 256, 0, stream>>>(wk, wk_bf);

  gemm_bt<u16><<<dim3(32, 32), 256, 0, stream>>>(x_bf, qkv_bf, qv_bf, 4096, 4096, 2048);
  gemm_bt<u16><<<dim3(9, 32), 256, 0, stream>>>(x_bf, wk_bf, kbuf, 4096, 1152, 2048);
  rope_scatter<<<4096, 256, 0, stream>>>(qv_bf, kbuf, q_bf, k_bf, k_out, S);
  v_scatter<<<8192, 256, 0, stream>>>(qv_bf, vt_bf, v_out, S);
  flash_attn2<<<1024, 256, 0, stream>>>(q_bf, k_bf, vt_bf, attn_bf, S);
  gemm_bt<float><<<dim3(16, 32), 256, 0, stream>>>(attn_bf, wo_bf, out, 4096, 2048, 2048);
}

// Round 4
// 328.642 us; speedup vs baseline: 2.1828x; 1.1501x over previous
//
#include <hip/hip_runtime.h>
#include <hip/hip_bf16.h>

// Decoupled RoPE MHA on MI355X (gfx950).
// B=2 S=2048 D=2048 H=16 dh=128 nope=64 rope=64
// R4: GEMMs upgraded to 256x256 8-phase template (T2 swizzle + T3/T4 counted
// vmcnt + T5 setprio); GEMM2 fused into GEMM1 (N=5376); Q rope'd in-place.

typedef unsigned short u16;
typedef unsigned int u32;
typedef __bf16 bf16x8 __attribute__((ext_vector_type(8)));
typedef float f32x4 __attribute__((ext_vector_type(4)));

__device__ __forceinline__ u16 f2bf(float x) {
  union { __hip_bfloat16 h; u16 u; } c;
  c.h = __float2bfloat16(x);
  return c.u;
}
__device__ __forceinline__ float bf2f(u16 u) {
  union { u32 u; float f; } c;
  c.u = ((u32)u) << 16;
  return c.f;
}
__device__ __forceinline__ f32x4 mfma16(bf16x8 a, bf16x8 b, f32x4 c) {
  return __builtin_amdgcn_mfma_f32_16x16x32_bf16(a, b, c, 0, 0, 0);
}
__device__ __forceinline__ void gload_lds16(const void* g, void* l) {
  __builtin_amdgcn_global_load_lds((__attribute__((address_space(1))) void*)g,
                                   (__attribute__((address_space(3))) void*)l,
                                   16, 0, 0);
}

// ---------------- cast kernels ----------------
__global__ void cast4(const float4* __restrict__ src, u16* __restrict__ dst, int nv) {
  int i = blockIdx.x * blockDim.x + threadIdx.x;
  if (i >= nv) return;
  float4 v = src[i];
  u32 lo = (u32)f2bf(v.x) | ((u32)f2bf(v.y) << 16);
  u32 hi = (u32)f2bf(v.z) | ((u32)f2bf(v.w) << 16);
  ((uint2*)dst)[i] = make_uint2(lo, hi);
}

// wk is (1088, 2048); pad to (1280, 2048) with zeros (rows 4096..5375 of Wcomb).
__global__ void cast_wk_pad(const float* __restrict__ src, u16* __restrict__ dst) {
  int i = blockIdx.x * blockDim.x + threadIdx.x;  // over 1280*2048/4 = 655360
  if (i >= 655360) return;
  int r = (i * 4) >> 11;
  u32 lo = 0, hi = 0;
  if (r < 1088) {
    float4 v = ((const float4*)src)[i];
    lo = (u32)f2bf(v.x) | ((u32)f2bf(v.y) << 16);
    hi = (u32)f2bf(v.z) | ((u32)f2bf(v.w) << 16);
  }
  ((uint2*)dst)[i] = make_uint2(lo, hi);
}

// ------------- GEMM 256x256, BK=64, 8-phase-style (4 phases/K-tile) ---------
// C[M,N] = A[M,K] @ W[N,K]^T. 8 waves (2M x 4N), 512 thr, LDS 128KB dbuf.
// LDS halves: A-h = rows [h*128,h*128+128) of the 256-row tile, same for B.
// Phase (Mh,Nh): all waves work the block-quadrant; wave slice 64x32.
// T2 swizzle: linear LDS dest (gload_lds), pre-swizzled global source,
// read addr byte ^= ((row&7)<<4). Counted vmcnt(4) once per K-tile.
// Stage schedule (tile t): p0:(t+1)A1  p1:(t+1)B1  p2:(t+2)A0  p3:(t+2)B0.
// Region lifetimes: A0 read p0-p1, B0 p0&p2, A1 p2-p3, B1 p1&p3 -> no overlap.
__device__ __forceinline__ void cstore(u16* C, size_t i, float v) { C[i] = f2bf(v); }
__device__ __forceinline__ void cstore(float* C, size_t i, float v) { C[i] = v; }

template <typename CT>
__global__ __launch_bounds__(512, 2) void gemm256(const u16* __restrict__ A,
                                                  const u16* __restrict__ W,
                                                  CT* __restrict__ C,
                                                  int M, int N, int K) {
  __shared__ char lds[131072];
  const int tid = threadIdx.x;
  const int wid = tid >> 6, lane = tid & 63;
  const int lr = lane & 15, lg = lane >> 4;
  const int wr = wid >> 2, wc = wid & 3;
  const int xorv = (lr & 7) << 4;
  // XCD-aware bijective swizzle (requires nwg % 8 == 0 -- both call sites ok)
  const int nwg = gridDim.x * gridDim.y;
  const int lin = blockIdx.y * gridDim.x + blockIdx.x;
  const int swz = (lin & 7) * (nwg >> 3) + (lin >> 3);
  const int m0 = (swz / gridDim.x) * 256;
  const int n0 = (swz % gridDim.x) * 256;
  const int nkt = K >> 6;

  f32x4 acc[8][4] = {};
  bf16x8 a[4][2], b[4][2];

  // per-thread stage sources (pre-swizzled): chunk0 rows 0-63, chunk1 rows 64-127
  const int o0 = tid * 16, o1 = 8192 + tid * 16;
  const int r0 = o0 >> 7, c0 = ((o0 & 127) ^ ((r0 & 7) << 4)) >> 1;
  const int r1 = o1 >> 7, c1 = ((o1 & 127) ^ ((r1 & 7) << 4)) >> 1;
  const u16* gA00 = A + (size_t)(m0 + r0) * K + c0;
  const u16* gA01 = A + (size_t)(m0 + r1) * K + c1;
  const u16* gA10 = gA00 + (size_t)128 * K;
  const u16* gA11 = gA01 + (size_t)128 * K;
  const u16* gB00 = W + (size_t)(n0 + r0) * K + c0;
  const u16* gB01 = W + (size_t)(n0 + r1) * K + c1;
  const u16* gB10 = gB00 + (size_t)128 * K;
  const u16* gB11 = gB01 + (size_t)128 * K;
  char* const ldest = lds + wid * 1024;  // HW adds lane*16

#define STAGE_A(t, h)                                                         \
  {                                                                           \
    char* d_ = ldest + ((t) & 1) * 32768 + (h) * 16384;                       \
    gload_lds16(((h) ? gA10 : gA00) + (t) * 64, d_);                          \
    gload_lds16(((h) ? gA11 : gA01) + (t) * 64, d_ + 8192);                   \
  }
#define STAGE_B(t, h)                                                         \
  {                                                                           \
    char* d_ = ldest + 65536 + ((t) & 1) * 32768 + (h) * 16384;               \
    gload_lds16(((h) ? gB10 : gB00) + (t) * 64, d_);                          \
    gload_lds16(((h) ? gB11 : gB01) + (t) * 64, d_ + 8192);                   \
  }

  // prologue: t0 {A0,B0,A1,B1}, t1 {A0,B0}; wait tile0 (oldest 8 loads)
  STAGE_A(0, 0); STAGE_B(0, 0); STAGE_A(0, 1); STAGE_B(0, 1);
  if (nkt > 1) { STAGE_A(1, 0); STAGE_B(1, 0); }
  asm volatile("s_waitcnt vmcnt(4)" ::: "memory");
  __builtin_amdgcn_s_barrier();

  for (int t = 0; t < nkt; ++t) {
    const char* Ab = lds + (t & 1) * 32768;
    const char* Bb = lds + 65536 + (t & 1) * 32768;
    const int arow = wr * 64, browb = wc * 32;
    // ---- phase 0: (Mh0, Nh0) ----
#pragma unroll
    for (int mi = 0; mi < 4; mi++)
#pragma unroll
      for (int ks = 0; ks < 2; ks++)
        a[mi][ks] = *(const bf16x8*)(Ab + (arow + mi * 16 + lr) * 128 + ((lg * 16 + ks * 64) ^ xorv));
#pragma unroll
    for (int ni = 0; ni < 2; ni++)
#pragma unroll
      for (int ks = 0; ks < 2; ks++)
        b[ni][ks] = *(const bf16x8*)(Bb + (browb + ni * 16 + lr) * 128 + ((lg * 16 + ks * 64) ^ xorv));
    if (t + 1 < nkt) STAGE_A(t + 1, 1);
    __builtin_amdgcn_s_barrier();
    asm volatile("s_waitcnt lgkmcnt(0)" ::: "memory");
    __builtin_amdgcn_sched_barrier(0);
    __builtin_amdgcn_s_setprio(1);
#pragma unroll
    for (int mi = 0; mi < 4; mi++)
#pragma unroll
      for (int ni = 0; ni < 2; ni++)
#pragma unroll
        for (int ks = 0; ks < 2; ks++)
          acc[mi][ni] = mfma16(a[mi][ks], b[ni][ks], acc[mi][ni]);
    __builtin_amdgcn_s_setprio(0);
    __builtin_amdgcn_s_barrier();
    // ---- phase 1: (Mh0, Nh1) ----
#pragma unroll
    for (int ni = 0; ni < 2; ni++)
#pragma unroll
      for (int ks = 0; ks < 2; ks++)
        b[2 + ni][ks] = *(const bf16x8*)(Bb + 16384 + (browb + ni * 16 + lr) * 128 + ((lg * 16 + ks * 64) ^ xorv));
    if (t + 1 < nkt) STAGE_B(t + 1, 1);
    __builtin_amdgcn_s_barrier();
    asm volatile("s_waitcnt lgkmcnt(0)" ::: "memory");
    __builtin_amdgcn_sched_barrier(0);
    __builtin_amdgcn_s_setprio(1);
#pragma unroll
    for (int mi = 0; mi < 4; mi++)
#pragma unroll
      for (int ni = 0; ni < 2; ni++)
#pragma unroll
        for (int ks = 0; ks < 2; ks++)
          acc[mi][2 + ni] = mfma16(a[mi][ks], b[2 + ni][ks], acc[mi][2 + ni]);
    __builtin_amdgcn_s_setprio(0);
    __builtin_amdgcn_s_barrier();
    // ---- phase 2: (Mh1, Nh0) ----
#pragma unroll
    for (int mi = 0; mi < 4; mi++)
#pragma unroll
      for (int ks = 0; ks < 2; ks++)
        a[mi][ks] = *(const bf16x8*)(Ab + 16384 + (arow + mi * 16 + lr) * 128 + ((lg * 16 + ks * 64) ^ xorv));
    if (t + 2 < nkt) STAGE_A(t + 2, 0);
    __builtin_amdgcn_s_barrier();
    asm volatile("s_waitcnt lgkmcnt(0)" ::: "memory");
    __builtin_amdgcn_sched_barrier(0);
    __builtin_amdgcn_s_setprio(1);
#pragma unroll
    for (int mi = 0; mi < 4; mi++)
#pragma unroll
      for (int ni = 0; ni < 2; ni++)
#pragma unroll
        for (int ks = 0; ks < 2; ks++)
          acc[4 + mi][ni] = mfma16(a[mi][ks], b[ni][ks], acc[4 + mi][ni]);
    __builtin_amdgcn_s_setprio(0);
    __builtin_amdgcn_s_barrier();
    // ---- phase 3: (Mh1, Nh1) ----
    if (t + 2 < nkt) {
      STAGE_B(t + 2, 0);
      asm volatile("s_waitcnt vmcnt(4)" ::: "memory");
    } else if (t + 1 < nkt) {
      asm volatile("s_waitcnt vmcnt(0)" ::: "memory");
    }
    __builtin_amdgcn_s_barrier();
    asm volatile("s_waitcnt lgkmcnt(0)" ::: "memory");
    __builtin_amdgcn_sched_barrier(0);
    __builtin_amdgcn_s_setprio(1);
#pragma unroll
    for (int mi = 0; mi < 4; mi++)
#pragma unroll
      for (int ni = 0; ni < 2; ni++)
#pragma unroll
        for (int ks = 0; ks < 2; ks++)
          acc[4 + mi][2 + ni] = mfma16(a[mi][ks], b[2 + ni][ks], acc[4 + mi][2 + ni]);
    __builtin_amdgcn_s_setprio(0);
    __builtin_amdgcn_s_barrier();
  }
#undef STAGE_A
#undef STAGE_B

  // epilogue: C row = m0 + Mh*128 + wr*64 + mi*16 + lg*4 + r; col = n0 + Nh*128 + wc*32 + ni*16 + lr
#pragma unroll
  for (int Mh = 0; Mh < 2; Mh++)
#pragma unroll
    for (int mi = 0; mi < 4; mi++) {
      int row = m0 + Mh * 128 + wr * 64 + mi * 16 + lg * 4;
#pragma unroll
      for (int Nh = 0; Nh < 2; Nh++)
#pragma unroll
        for (int ni = 0; ni < 2; ni++) {
          int col = n0 + Nh * 128 + wc * 32 + ni * 16 + lr;
#pragma unroll
          for (int r = 0; r < 4; r++)
            cstore(C, (size_t)(row + r) * N + col, acc[Mh * 4 + mi][Nh * 2 + ni][r]);
        }
    }
}

// ---------------- RoPE: Q in-place in QVK + K scatter ----------------
// QVK row (b*S+s): [Q 2048 | V 2048 | K 1152 | pad 128]. Kn = 4096+h*64+d,
// Kr = 5120..5183.
__global__ __launch_bounds__(256) void rope_scatter2(u16* __restrict__ QVK,
                                                     u16* __restrict__ kh,
                                                     float* __restrict__ k_out, int S) {
  const int row = blockIdx.x;  // b*S + s
  const int b = row >> 11, s = row & 2047;
  const int tid = threadIdx.x;
  __shared__ float kr[64];
  const float LOG1E4_64 = 0.14391156511f;  // ln(10000)/64
  u16* qrow = QVK + (size_t)row * 5376;
  if (tid < 32) {
    float freq = __expf(-(float)tid * LOG1E4_64);
    float sn, c;
    __sincosf((float)s * freq, &sn, &c);
    float a = bf2f(qrow[5120 + tid]);
    float bb = bf2f(qrow[5152 + tid]);
    kr[tid] = a * c - bb * sn;
    kr[tid + 32] = bb * c + a * sn;
  }
  // Q rope in-place: each thread owns a (h,jj) pair -> no cross-thread hazard
  for (int idx = tid; idx < 512; idx += 256) {
    int h = idx >> 5, jj = idx & 31;
    float freq = __expf(-(float)jj * LOG1E4_64);
    float sn, c;
    __sincosf((float)s * freq, &sn, &c);
    u16* p1 = qrow + h * 128 + 64 + jj;
    u16* p2 = qrow + h * 128 + 96 + jj;
    float x1 = bf2f(*p1), x2 = bf2f(*p2);
    *p1 = f2bf(x1 * c - x2 * sn);
    *p2 = f2bf(x2 * c + x1 * sn);
  }
  __syncthreads();
  for (int idx = tid; idx < 2048; idx += 256) {
    int h = idx >> 7, d = idx & 127;
    float val = (d < 64) ? bf2f(qrow[4096 + h * 64 + d]) : kr[d - 64];
    size_t o = ((size_t)(b * 16 + h) * S + s) * 128 + d;
    kh[o] = f2bf(val);
    k_out[o] = val;
  }
}

// ---------------- V: write v_heads fp32 + transposed Vt (B,H,128,S) ----------
__global__ __launch_bounds__(256) void v_scatter(const u16* __restrict__ QVK,
                                                 u16* __restrict__ vt,
                                                 float* __restrict__ v_out, int S) {
  const int blk = blockIdx.x;
  const int st = blk & 63;
  const int dt = (blk >> 6) & 3;
  const int bh = blk >> 8;
  const int b = bh >> 4, h = bh & 15;
  __shared__ u16 t[32][34];
  const int tx = threadIdx.x & 31, ty = threadIdx.x >> 5;
  const int s0 = st * 32, d0 = dt * 32;
#pragma unroll
  for (int i = 0; i < 4; i++) {
    int sl = ty + 8 * i;
    u16 u = QVK[(size_t)(b * S + s0 + sl) * 5376 + 2048 + h * 128 + d0 + tx];
    t[sl][tx] = u;
    v_out[((size_t)bh * S + s0 + sl) * 128 + d0 + tx] = bf2f(u);
  }
  __syncthreads();
#pragma unroll
  for (int i = 0; i < 4; i++) {
    int dl = ty + 8 * i;
    vt[((size_t)bh * 128 + d0 + dl) * S + s0 + tx] = t[tx][dl];
  }
}

// ---------------- flash attention (causal, LDS-staged K/V) ----------------
__global__ __launch_bounds__(256) void flash_attn2(const u16* __restrict__ QVK,
                                                   const u16* __restrict__ Kh,
                                                   const u16* __restrict__ Vt,
                                                   u16* __restrict__ attn, int S) {
  __shared__ char lds[65536];
  const int tid = threadIdx.x, wid = tid >> 6, lane = tid & 63;
  const int bh = blockIdx.x & 31;
  const int qb = 31 - (int)(blockIdx.x >> 5);  // longest q-blocks first
  const int q0 = qb * 64 + wid * 16;
  const int b = bh >> 4, h = bh & 15;
  const int q = lane & 15, g = lane >> 4;
  const u16* Qb = QVK + (size_t)b * S * 5376 + h * 128;
  const u16* Kb = Kh + (size_t)bh * S * 128;
  const u16* Vb = Vt + (size_t)bh * 128 * S;
  const int qg = q0 + q;
  const int xr = (q & 7) << 4;

  const u16* srcK[4];
  const u16* srcV[4];
#pragma unroll
  for (int i = 0; i < 4; i++) {
    int o = ((i * 4 + wid) << 10) | (lane << 4);
    int rK = o >> 8, cbK = (o & 255) ^ ((rK & 7) << 4);
    srcK[i] = Kb + rK * 128 + (cbK >> 1);
    int dV = o >> 7, kbV = (o & 127) ^ ((dV & 7) << 4);
    srcV[i] = Vb + (size_t)dV * S + (kbV >> 1);
  }

  bf16x8 qf[4];
#pragma unroll
  for (int f = 0; f < 4; f++)
    qf[f] = *(const bf16x8*)(Qb + (size_t)qg * 5376 + f * 32 + g * 8);

  f32x4 acc[8] = {};
  float m = -INFINITY, l = 0.f;
  const float sc = 0.08838834764831845f;  // 1/sqrt(128)
  const int ktiles = qb + 1;

#pragma unroll
  for (int i = 0; i < 4; i++) {
    char* ld = lds + ((i * 4 + wid) << 10);
    gload_lds16(srcK[i], ld);
    gload_lds16(srcV[i], ld + 32768);
  }
  asm volatile("s_waitcnt vmcnt(0)" ::: "memory");
  __syncthreads();

  int buf = 0;
  for (int kt = 0; kt < ktiles; ++kt) {
    if (kt + 1 < ktiles) {
      const int nb = buf ^ 1;
      const int adv = (kt + 1) * 8192;
      const int advv = (kt + 1) * 64;
#pragma unroll
      for (int i = 0; i < 4; i++) {
        char* ld = lds + nb * 16384 + ((i * 4 + wid) << 10);
        gload_lds16(srcK[i] + adv, ld);
        gload_lds16(srcV[i] + advv, ld + 32768);
      }
    }
    const char* Kt = lds + buf * 16384;
    const char* Vl = lds + 32768 + buf * 16384;

#pragma unroll
    for (int sub = 0; sub < 2; ++sub) {
      const int kb2 = sub * 32;
      const int kbg = kt * 64 + kb2;
      if (kbg > q0 + 15) break;  // wave-uniform: fully masked
      f32x4 s0 = {0.f, 0.f, 0.f, 0.f}, s1 = {0.f, 0.f, 0.f, 0.f};
      const char* Kq = Kt + (kb2 + q) * 256;
      __builtin_amdgcn_s_setprio(1);
#pragma unroll
      for (int f = 0; f < 4; f++) {
        bf16x8 k0 = *(const bf16x8*)(Kq + ((f * 64 + g * 16) ^ xr));
        bf16x8 k1 = *(const bf16x8*)(Kq + 4096 + ((f * 64 + g * 16) ^ xr));
        s0 = mfma16(k0, qf[f], s0);
        s1 = mfma16(k1, qf[f], s1);
      }
      __builtin_amdgcn_s_setprio(0);
      float v[8];
      const bool maskt = (kbg + 31 > q0);
#pragma unroll
      for (int r = 0; r < 4; r++) {
        int key0 = kbg + g * 4 + r;
        v[r] = s0[r] * sc;
        v[4 + r] = s1[r] * sc;
        if (maskt) {
          if (key0 > qg) v[r] = -1e30f;
          if (key0 + 16 > qg) v[4 + r] = -1e30f;
        }
      }
      float tm = v[0];
#pragma unroll
      for (int i = 1; i < 8; i++) tm = fmaxf(tm, v[i]);
      tm = fmaxf(tm, __shfl_xor(tm, 16));
      tm = fmaxf(tm, __shfl_xor(tm, 32));
      float mnew = fmaxf(m, tm);
      float corr = __expf(m - mnew);
      float p[8];
      float ts = 0.f;
#pragma unroll
      for (int i = 0; i < 8; i++) {
        p[i] = __expf(v[i] - mnew);
        ts += p[i];
      }
      ts += __shfl_xor(ts, 16);
      ts += __shfl_xor(ts, 32);
      l = l * corr + ts;
      m = mnew;
      float corr_r[4];
#pragma unroll
      for (int r = 0; r < 4; r++)
        corr_r[r] = __shfl(corr, (lane & 48) | (g * 4 + r));
#pragma unroll
      for (int j = 0; j < 8; j++)
#pragma unroll
        for (int r = 0; r < 4; r++) acc[j][r] *= corr_r[r];
      u32 w0a = (u32)f2bf(p[0]) | ((u32)f2bf(p[1]) << 16);
      u32 w0b = (u32)f2bf(p[2]) | ((u32)f2bf(p[3]) << 16);
      u32 w1a = (u32)f2bf(p[4]) | ((u32)f2bf(p[5]) << 16);
      u32 w1b = (u32)f2bf(p[6]) | ((u32)f2bf(p[7]) << 16);
      int src0 = q | ((g & 1) << 5);
      u32 a_lo  = (u32)__shfl((int)w0a, src0);
      u32 b_lo  = (u32)__shfl((int)w0b, src0);
      u32 a_lo2 = (u32)__shfl((int)w0a, src0 + 16);
      u32 b_lo2 = (u32)__shfl((int)w0b, src0 + 16);
      u32 a_hi  = (u32)__shfl((int)w1a, src0);
      u32 b_hi  = (u32)__shfl((int)w1b, src0);
      u32 a_hi2 = (u32)__shfl((int)w1a, src0 + 16);
      u32 b_hi2 = (u32)__shfl((int)w1b, src0 + 16);
      const bool hi = (g & 2);
      union { u32 u[4]; bf16x8 v; } pc;
      pc.u[0] = hi ? a_hi : a_lo;
      pc.u[1] = hi ? b_hi : b_lo;
      pc.u[2] = hi ? a_hi2 : a_lo2;
      pc.u[3] = hi ? b_hi2 : b_lo2;
      const int vcol = (sub * 64 + g * 16) ^ xr;
      __builtin_amdgcn_s_setprio(1);
#pragma unroll
      for (int j = 0; j < 8; j++) {
        bf16x8 vf = *(const bf16x8*)(Vl + (j * 16 + q) * 128 + vcol);
        acc[j] = mfma16(pc.v, vf, acc[j]);
      }
      __builtin_amdgcn_s_setprio(0);
    }
    asm volatile("s_waitcnt vmcnt(0)" ::: "memory");
    __syncthreads();
    buf ^= 1;
  }

  float linv = 1.0f / l;
  float linv_r[4];
#pragma unroll
  for (int r = 0; r < 4; r++)
    linv_r[r] = __shfl(linv, (lane & 48) | (g * 4 + r));
  u16* ab = attn + (size_t)(b * S + q0) * 2048 + h * 128;
#pragma unroll
  for (int j = 0; j < 8; j++)
#pragma unroll
    for (int r = 0; r < 4; r++)
      ab[(size_t)(g * 4 + r) * 2048 + j * 16 + q] = f2bf(acc[j][r] * linv_r[r]);
}

// ---------------- launch ----------------
extern "C" void kernel_launch(void* const* d_in, const int* in_sizes, int n_in,
                              void* d_out, int out_size, void* d_ws, size_t ws_size,
                              hipStream_t stream) {
  (void)in_sizes; (void)n_in; (void)out_size; (void)ws_size;
  const int S = 2048;
  const float* x = (const float*)d_in[0];
  const float* qkv = (const float*)d_in[1];
  const float* wk = (const float*)d_in[2];
  const float* wo = (const float*)d_in[3];
  float* out = (float*)d_out;
  float* k_out = out + (size_t)8388608;
  float* v_out = out + (size_t)16777216;

  char* ws = (char*)d_ws;
  // workspace layout (108.0 MB); attn aliases x_bf, k_bf aliases wcomb
  u16* x_bf  = (u16*)(ws + 0);          // 16.78 MB (later: attn_bf)
  u16* wcomb = (u16*)(ws + 16777216);   // 22.02 MB (5376x2048) (later: k_bf)
  u16* wo_bf = (u16*)(ws + 38797312);   // 8.39 MB
  u16* qvk   = (u16*)(ws + 47185920);   // 44.04 MB (4096x5376)
  u16* vt_bf = (u16*)(ws + 91226112);   // 16.78 MB (B,H,128,S)
  u16* attn_bf = x_bf;
  u16* k_bf = wcomb;

  cast4<<<8192, 256, 0, stream>>>((const float4*)x, x_bf, 2097152);
  cast4<<<8192, 256, 0, stream>>>((const float4*)qkv, wcomb, 2097152);
  cast_wk_pad<<<2560, 256, 0, stream>>>(wk, wcomb + 8388608);
  cast4<<<4096, 256, 0, stream>>>((const float4*)wo, wo_bf, 1048576);

  gemm256<u16><<<dim3(21, 16), 512, 0, stream>>>(x_bf, wcomb, qvk, 4096, 5376, 2048);
  rope_scatter2<<<4096, 256, 0, stream>>>(qvk, k_bf, k_out, S);
  v_scatter<<<8192, 256, 0, stream>>>(qvk, vt_bf, v_out, S);
  flash_attn2<<<1024, 256, 0, stream>>>(qvk, k_bf, vt_bf, attn_bf, S);
  gemm256<float><<<dim3(8, 16), 512, 0, stream>>>(attn_bf, wo_bf, out, 4096, 2048, 2048);
}

// Round 5
// 289.344 us; speedup vs baseline: 2.4793x; 1.1358x over previous
//
#include <hip/hip_runtime.h>
#include <hip/hip_bf16.h>

// Decoupled RoPE MHA on MI355X (gfx950).
// B=2 S=2048 D=2048 H=16 dh=128 nope=64 rope=64
// R5: gemm256 templated on BM (gemm3 uses BM=128 -> 256 balanced blocks);
// flash: merged 64-key softmax + defer-max + exp-folded scale; fused casts.

typedef unsigned short u16;
typedef unsigned int u32;
typedef __bf16 bf16x8 __attribute__((ext_vector_type(8)));
typedef float f32x4 __attribute__((ext_vector_type(4)));

__device__ __forceinline__ u16 f2bf(float x) {
  union { __hip_bfloat16 h; u16 u; } c;
  c.h = __float2bfloat16(x);
  return c.u;
}
__device__ __forceinline__ float bf2f(u16 u) {
  union { u32 u; float f; } c;
  c.u = ((u32)u) << 16;
  return c.f;
}
__device__ __forceinline__ f32x4 mfma16(bf16x8 a, bf16x8 b, f32x4 c) {
  return __builtin_amdgcn_mfma_f32_16x16x32_bf16(a, b, c, 0, 0, 0);
}
__device__ __forceinline__ void gload_lds16(const void* g, void* l) {
  __builtin_amdgcn_global_load_lds((__attribute__((address_space(1))) void*)g,
                                   (__attribute__((address_space(3))) void*)l,
                                   16, 0, 0);
}

// ---------------- fused cast kernel ----------------
// segments (float4 units): x 2097152 | qkv 2097152 | wk-pad 655360 | wo 1048576
__global__ __launch_bounds__(256) void cast_all(const float4* __restrict__ x,
                                                const float4* __restrict__ qkv,
                                                const float* __restrict__ wk,
                                                const float4* __restrict__ wo,
                                                u16* __restrict__ x_bf,
                                                u16* __restrict__ wcomb,
                                                u16* __restrict__ wo_bf) {
  int i = blockIdx.x * blockDim.x + threadIdx.x;
  const float4* src;
  u16* dst;
  int j;
  if (i < 2097152) {
    src = x; dst = x_bf; j = i;
  } else if (i < 4194304) {
    src = qkv; dst = wcomb; j = i - 2097152;
  } else if (i < 4849664) {
    j = i - 4194304;  // over 1280x2048/4; rows >=1088 are zero pad
    int r = (j * 4) >> 11;
    u32 lo = 0, hi = 0;
    if (r < 1088) {
      float4 v = ((const float4*)wk)[j];
      lo = (u32)f2bf(v.x) | ((u32)f2bf(v.y) << 16);
      hi = (u32)f2bf(v.z) | ((u32)f2bf(v.w) << 16);
    }
    ((uint2*)(wcomb + 8388608))[j] = make_uint2(lo, hi);
    return;
  } else {
    src = wo; dst = wo_bf; j = i - 4849664;
  }
  float4 v = src[j];
  u32 lo = (u32)f2bf(v.x) | ((u32)f2bf(v.y) << 16);
  u32 hi = (u32)f2bf(v.z) | ((u32)f2bf(v.w) << 16);
  ((uint2*)dst)[j] = make_uint2(lo, hi);
}

// ------------- GEMM BMx256, BK=64, 4 phases/K-tile, templated BM ------------
// C[M,N] = A[M,K] @ W[N,K]^T. 8 waves (2M x 4N), 512 thr, double-buffered LDS.
// T2 swizzle: linear LDS dest (gload_lds), pre-swizzled global source,
// read addr byte ^= ((row&7)<<4). Counted vmcnt once per K-tile.
// Stage schedule (tile t): p0:(t+1)A1  p1:(t+1)B1  p2:(t+2)A0  p3:(t+2)B0.
__device__ __forceinline__ void cstore(u16* C, size_t i, float v) { C[i] = f2bf(v); }
__device__ __forceinline__ void cstore(float* C, size_t i, float v) { C[i] = v; }

template <typename CT, int BM>
__global__ __launch_bounds__(512, 2) void gemm256(const u16* __restrict__ A,
                                                  const u16* __restrict__ W,
                                                  CT* __restrict__ C,
                                                  int M, int N, int K) {
  constexpr int MI = BM / 64;       // a-frags per quadrant (4 or 2)
  constexpr int AH = BM * 64;       // bytes per A half-tile (16K or 8K)
  constexpr int AL = BM / 128;      // gloads/thread per A half (2 or 1)
  constexpr int BOFF = 4 * AH;      // B region base in LDS
  __shared__ char lds[BOFF + 65536];
  const int tid = threadIdx.x;
  const int wid = tid >> 6, lane = tid & 63;
  const int lr = lane & 15, lg = lane >> 4;
  const int wr = wid >> 2, wc = wid & 3;
  const int xorv = (lr & 7) << 4;
  // XCD-aware bijective swizzle (nwg % 8 == 0 at both call sites)
  const int nwg = gridDim.x * gridDim.y;
  const int lin = blockIdx.y * gridDim.x + blockIdx.x;
  const int swz = (lin & 7) * (nwg >> 3) + (lin >> 3);
  const int m0 = (swz / gridDim.x) * BM;
  const int n0 = (swz % gridDim.x) * 256;
  const int nkt = K >> 6;

  f32x4 acc[2 * MI][4] = {};
  bf16x8 a[MI][2], b[4][2];

  // per-thread stage sources (pre-swizzled)
  const int o0 = tid * 16, o1 = 8192 + tid * 16;
  const int r0 = o0 >> 7, c0 = ((o0 & 127) ^ ((r0 & 7) << 4)) >> 1;
  const int r1 = o1 >> 7, c1 = ((o1 & 127) ^ ((r1 & 7) << 4)) >> 1;
  const u16* gA0[2] = {A + (size_t)(m0 + r0) * K + c0,
                       A + (size_t)(m0 + BM / 2 + r0) * K + c0};
  const u16* gA1[2] = {A + (size_t)(m0 + r1) * K + c1,
                       A + (size_t)(m0 + BM / 2 + r1) * K + c1};
  const u16* gB0[2] = {W + (size_t)(n0 + r0) * K + c0,
                       W + (size_t)(n0 + 128 + r0) * K + c0};
  const u16* gB1[2] = {W + (size_t)(n0 + r1) * K + c1,
                       W + (size_t)(n0 + 128 + r1) * K + c1};

  auto STAGEA = [&](int t, int h) {
    char* d_ = lds + (t & 1) * (2 * AH) + h * AH + wid * 1024;
    gload_lds16(gA0[h] + (size_t)t * 64, d_);
    if constexpr (AL == 2) gload_lds16(gA1[h] + (size_t)t * 64, d_ + 8192);
  };
  auto STAGEB = [&](int t, int h) {
    char* d_ = lds + BOFF + (t & 1) * 32768 + h * 16384 + wid * 1024;
    gload_lds16(gB0[h] + (size_t)t * 64, d_);
    gload_lds16(gB1[h] + (size_t)t * 64, d_ + 8192);
  };
  auto WAITKEEP = [&]() {  // keep (t+2)A0+(t+2)B0 in flight
    if constexpr (BM == 256) asm volatile("s_waitcnt vmcnt(4)" ::: "memory");
    else asm volatile("s_waitcnt vmcnt(3)" ::: "memory");
  };

  // prologue
  STAGEA(0, 0); STAGEB(0, 0); STAGEA(0, 1); STAGEB(0, 1);
  if (nkt > 1) { STAGEA(1, 0); STAGEB(1, 0); }
  WAITKEEP();
  __builtin_amdgcn_s_barrier();

  for (int t = 0; t < nkt; ++t) {
    const char* Ab = lds + (t & 1) * (2 * AH);
    const char* Bb = lds + BOFF + (t & 1) * 32768;
    const int arow = wr * (BM / 4), brow = wc * 32;
    // ---- phase 0: (Mh0, Nh0) ----
#pragma unroll
    for (int mi = 0; mi < MI; mi++)
#pragma unroll
      for (int ks = 0; ks < 2; ks++)
        a[mi][ks] = *(const bf16x8*)(Ab + (arow + mi * 16 + lr) * 128 + ((lg * 16 + ks * 64) ^ xorv));
#pragma unroll
    for (int ni = 0; ni < 2; ni++)
#pragma unroll
      for (int ks = 0; ks < 2; ks++)
        b[ni][ks] = *(const bf16x8*)(Bb + (brow + ni * 16 + lr) * 128 + ((lg * 16 + ks * 64) ^ xorv));
    if (t + 1 < nkt) STAGEA(t + 1, 1);
    __builtin_amdgcn_s_barrier();
    asm volatile("s_waitcnt lgkmcnt(0)" ::: "memory");
    __builtin_amdgcn_sched_barrier(0);
    __builtin_amdgcn_s_setprio(1);
#pragma unroll
    for (int mi = 0; mi < MI; mi++)
#pragma unroll
      for (int ni = 0; ni < 2; ni++)
#pragma unroll
        for (int ks = 0; ks < 2; ks++)
          acc[mi][ni] = mfma16(a[mi][ks], b[ni][ks], acc[mi][ni]);
    __builtin_amdgcn_s_setprio(0);
    __builtin_amdgcn_s_barrier();
    // ---- phase 1: (Mh0, Nh1) ----
#pragma unroll
    for (int ni = 0; ni < 2; ni++)
#pragma unroll
      for (int ks = 0; ks < 2; ks++)
        b[2 + ni][ks] = *(const bf16x8*)(Bb + 16384 + (brow + ni * 16 + lr) * 128 + ((lg * 16 + ks * 64) ^ xorv));
    if (t + 1 < nkt) STAGEB(t + 1, 1);
    __builtin_amdgcn_s_barrier();
    asm volatile("s_waitcnt lgkmcnt(0)" ::: "memory");
    __builtin_amdgcn_sched_barrier(0);
    __builtin_amdgcn_s_setprio(1);
#pragma unroll
    for (int mi = 0; mi < MI; mi++)
#pragma unroll
      for (int ni = 0; ni < 2; ni++)
#pragma unroll
        for (int ks = 0; ks < 2; ks++)
          acc[mi][2 + ni] = mfma16(a[mi][ks], b[2 + ni][ks], acc[mi][2 + ni]);
    __builtin_amdgcn_s_setprio(0);
    __builtin_amdgcn_s_barrier();
    // ---- phase 2: (Mh1, Nh0) ----
#pragma unroll
    for (int mi = 0; mi < MI; mi++)
#pragma unroll
      for (int ks = 0; ks < 2; ks++)
        a[mi][ks] = *(const bf16x8*)(Ab + AH + (arow + mi * 16 + lr) * 128 + ((lg * 16 + ks * 64) ^ xorv));
    if (t + 2 < nkt) STAGEA(t + 2, 0);
    __builtin_amdgcn_s_barrier();
    asm volatile("s_waitcnt lgkmcnt(0)" ::: "memory");
    __builtin_amdgcn_sched_barrier(0);
    __builtin_amdgcn_s_setprio(1);
#pragma unroll
    for (int mi = 0; mi < MI; mi++)
#pragma unroll
      for (int ni = 0; ni < 2; ni++)
#pragma unroll
        for (int ks = 0; ks < 2; ks++)
          acc[MI + mi][ni] = mfma16(a[mi][ks], b[ni][ks], acc[MI + mi][ni]);
    __builtin_amdgcn_s_setprio(0);
    __builtin_amdgcn_s_barrier();
    // ---- phase 3: (Mh1, Nh1) ----
    if (t + 2 < nkt) {
      STAGEB(t + 2, 0);
      WAITKEEP();
    } else if (t + 1 < nkt) {
      asm volatile("s_waitcnt vmcnt(0)" ::: "memory");
    }
    __builtin_amdgcn_s_barrier();
    asm volatile("s_waitcnt lgkmcnt(0)" ::: "memory");
    __builtin_amdgcn_sched_barrier(0);
    __builtin_amdgcn_s_setprio(1);
#pragma unroll
    for (int mi = 0; mi < MI; mi++)
#pragma unroll
      for (int ni = 0; ni < 2; ni++)
#pragma unroll
        for (int ks = 0; ks < 2; ks++)
          acc[MI + mi][2 + ni] = mfma16(a[mi][ks], b[2 + ni][ks], acc[MI + mi][2 + ni]);
    __builtin_amdgcn_s_setprio(0);
    __builtin_amdgcn_s_barrier();
  }

  // epilogue
#pragma unroll
  for (int Mh = 0; Mh < 2; Mh++)
#pragma unroll
    for (int mi = 0; mi < MI; mi++) {
      int row = m0 + Mh * (BM / 2) + wr * (BM / 4) + mi * 16 + lg * 4;
#pragma unroll
      for (int Nh = 0; Nh < 2; Nh++)
#pragma unroll
        for (int ni = 0; ni < 2; ni++) {
          int col = n0 + Nh * 128 + wc * 32 + ni * 16 + lr;
#pragma unroll
          for (int r = 0; r < 4; r++)
            cstore(C, (size_t)(row + r) * N + col, acc[Mh * MI + mi][Nh * 2 + ni][r]);
        }
    }
}

// ---------------- RoPE: Q in-place in QVK + K scatter ----------------
// QVK row (b*S+s): [Q 2048 | V 2048 | K 1152 | pad 128].
__global__ __launch_bounds__(256) void rope_scatter2(u16* __restrict__ QVK,
                                                     u16* __restrict__ kh,
                                                     float* __restrict__ k_out, int S) {
  const int row = blockIdx.x;  // b*S + s
  const int b = row >> 11, s = row & 2047;
  const int tid = threadIdx.x;
  __shared__ float kr[64];
  const float LOG1E4_64 = 0.14391156511f;  // ln(10000)/64
  u16* qrow = QVK + (size_t)row * 5376;
  if (tid < 32) {
    float freq = __expf(-(float)tid * LOG1E4_64);
    float sn, c;
    __sincosf((float)s * freq, &sn, &c);
    float a = bf2f(qrow[5120 + tid]);
    float bb = bf2f(qrow[5152 + tid]);
    kr[tid] = a * c - bb * sn;
    kr[tid + 32] = bb * c + a * sn;
  }
  for (int idx = tid; idx < 512; idx += 256) {
    int h = idx >> 5, jj = idx & 31;
    float freq = __expf(-(float)jj * LOG1E4_64);
    float sn, c;
    __sincosf((float)s * freq, &sn, &c);
    u16* p1 = qrow + h * 128 + 64 + jj;
    u16* p2 = qrow + h * 128 + 96 + jj;
    float x1 = bf2f(*p1), x2 = bf2f(*p2);
    *p1 = f2bf(x1 * c - x2 * sn);
    *p2 = f2bf(x2 * c + x1 * sn);
  }
  __syncthreads();
  for (int idx = tid; idx < 2048; idx += 256) {
    int h = idx >> 7, d = idx & 127;
    float val = (d < 64) ? bf2f(qrow[4096 + h * 64 + d]) : kr[d - 64];
    size_t o = ((size_t)(b * 16 + h) * S + s) * 128 + d;
    kh[o] = f2bf(val);
    k_out[o] = val;
  }
}

// ---------------- V: write v_heads fp32 + transposed Vt (B,H,128,S) ----------
__global__ __launch_bounds__(256) void v_scatter(const u16* __restrict__ QVK,
                                                 u16* __restrict__ vt,
                                                 float* __restrict__ v_out, int S) {
  const int blk = blockIdx.x;
  const int st = blk & 63;
  const int dt = (blk >> 6) & 3;
  const int bh = blk >> 8;
  const int b = bh >> 4, h = bh & 15;
  __shared__ u16 t[32][34];
  const int tx = threadIdx.x & 31, ty = threadIdx.x >> 5;
  const int s0 = st * 32, d0 = dt * 32;
#pragma unroll
  for (int i = 0; i < 4; i++) {
    int sl = ty + 8 * i;
    u16 u = QVK[(size_t)(b * S + s0 + sl) * 5376 + 2048 + h * 128 + d0 + tx];
    t[sl][tx] = u;
    v_out[((size_t)bh * S + s0 + sl) * 128 + d0 + tx] = bf2f(u);
  }
  __syncthreads();
#pragma unroll
  for (int i = 0; i < 4; i++) {
    int dl = ty + 8 * i;
    vt[((size_t)bh * 128 + d0 + dl) * S + s0 + tx] = t[tx][dl];
  }
}

// ---------------- flash attention (causal, LDS K/V, 64-key softmax) ---------
__global__ __launch_bounds__(256) void flash_attn2(const u16* __restrict__ QVK,
                                                   const u16* __restrict__ Kh,
                                                   const u16* __restrict__ Vt,
                                                   u16* __restrict__ attn, int S) {
  __shared__ char lds[65536];
  const int tid = threadIdx.x, wid = tid >> 6, lane = tid & 63;
  const int bh = blockIdx.x & 31;
  const int qb = 31 - (int)(blockIdx.x >> 5);  // longest q-blocks first
  const int q0 = qb * 64 + wid * 16;
  const int b = bh >> 4, h = bh & 15;
  const int q = lane & 15, g = lane >> 4;
  const u16* Qb = QVK + (size_t)b * S * 5376 + h * 128;
  const u16* Kb = Kh + (size_t)bh * S * 128;
  const u16* Vb = Vt + (size_t)bh * 128 * S;
  const int qg = q0 + q;
  const int xr = (q & 7) << 4;

  const u16* srcK[4];
  const u16* srcV[4];
#pragma unroll
  for (int i = 0; i < 4; i++) {
    int o = ((i * 4 + wid) << 10) | (lane << 4);
    int rK = o >> 8, cbK = (o & 255) ^ ((rK & 7) << 4);
    srcK[i] = Kb + rK * 128 + (cbK >> 1);
    int dV = o >> 7, kbV = (o & 127) ^ ((dV & 7) << 4);
    srcV[i] = Vb + (size_t)dV * S + (kbV >> 1);
  }

  bf16x8 qf[4];
#pragma unroll
  for (int f = 0; f < 4; f++)
    qf[f] = *(const bf16x8*)(Qb + (size_t)qg * 5376 + f * 32 + g * 8);

  f32x4 acc[8] = {};
  float m = -INFINITY, l = 0.f;
  const float sc = 0.08838834764831845f;  // 1/sqrt(128)
  const int ktiles = qb + 1;

#pragma unroll
  for (int i = 0; i < 4; i++) {
    char* ld = lds + ((i * 4 + wid) << 10);
    gload_lds16(srcK[i], ld);
    gload_lds16(srcV[i], ld + 32768);
  }
  asm volatile("s_waitcnt vmcnt(0)" ::: "memory");
  __syncthreads();

  int buf = 0;
  for (int kt = 0; kt < ktiles; ++kt) {
    if (kt + 1 < ktiles) {
      const int nb = buf ^ 1;
      const int adv = (kt + 1) * 8192;
      const int advv = (kt + 1) * 64;
#pragma unroll
      for (int i = 0; i < 4; i++) {
        char* ld = lds + nb * 16384 + ((i * 4 + wid) << 10);
        gload_lds16(srcK[i] + adv, ld);
        gload_lds16(srcV[i] + advv, ld + 32768);
      }
    }
    const char* Kt = lds + buf * 16384;
    const char* Vl = lds + 32768 + buf * 16384;

    // ---- QK^T for all 64 keys: s[c] holds keys kb + c*16 + g*4 + r ----
    f32x4 s[4] = {};
    const char* Kq = Kt + q * 256;
    __builtin_amdgcn_s_setprio(1);
#pragma unroll
    for (int f = 0; f < 4; f++) {
#pragma unroll
      for (int c = 0; c < 4; c++) {
        bf16x8 kf = *(const bf16x8*)(Kq + c * 4096 + ((f * 64 + g * 16) ^ xr));
        s[c] = mfma16(kf, qf[f], s[c]);
      }
    }
    __builtin_amdgcn_s_setprio(0);

    const int kbg = kt * 64;
    float v[16];
    const bool maskt = (kbg + 63 > q0);
#pragma unroll
    for (int c = 0; c < 4; c++)
#pragma unroll
      for (int r = 0; r < 4; r++) {
        float x = s[c][r];
        if (maskt && (kbg + c * 16 + g * 4 + r > qg)) x = -1e30f;
        v[c * 4 + r] = x;
      }
    float tm = v[0];
#pragma unroll
    for (int i = 1; i < 16; i++) tm = fmaxf(tm, v[i]);
    tm = fmaxf(tm, __shfl_xor(tm, 16));
    tm = fmaxf(tm, __shfl_xor(tm, 32));
    // defer-max: only rescale when raw max grew by > 64 (5.7 nats scaled)
    if (!__all(tm <= m + 64.0f)) {
      float mnew = fmaxf(m, tm);
      float corr = __expf((m - mnew) * sc);
      m = mnew;
      l *= corr;
      float corr_r[4];
#pragma unroll
      for (int r = 0; r < 4; r++)
        corr_r[r] = __shfl(corr, (lane & 48) | (g * 4 + r));
#pragma unroll
      for (int j = 0; j < 8; j++)
#pragma unroll
        for (int r = 0; r < 4; r++) acc[j][r] *= corr_r[r];
    }
    const float nms = -m * sc;
    float p[16], ts = 0.f;
#pragma unroll
    for (int i = 0; i < 16; i++) {
      p[i] = __expf(fmaf(v[i], sc, nms));
      ts += p[i];
    }
    ts += __shfl_xor(ts, 16);
    ts += __shfl_xor(ts, 32);
    l += ts;

    // P redistribution: dst lane (g,q) needs keys [g*8,g*8+8) (+32 for pcB) of
    // query q; shuffle both halves, select by dst (g&2).
    const int src0 = q | ((g & 1) << 5);
    const bool hi = (g & 2);
    union { u32 u[4]; bf16x8 v; } pcA, pcB;
    {
      u32 w0a = (u32)f2bf(p[0]) | ((u32)f2bf(p[1]) << 16);
      u32 w0b = (u32)f2bf(p[2]) | ((u32)f2bf(p[3]) << 16);
      u32 w1a = (u32)f2bf(p[4]) | ((u32)f2bf(p[5]) << 16);
      u32 w1b = (u32)f2bf(p[6]) | ((u32)f2bf(p[7]) << 16);
      u32 a_lo  = (u32)__shfl((int)w0a, src0);
      u32 b_lo  = (u32)__shfl((int)w0b, src0);
      u32 a_lo2 = (u32)__shfl((int)w0a, src0 + 16);
      u32 b_lo2 = (u32)__shfl((int)w0b, src0 + 16);
      u32 a_hi  = (u32)__shfl((int)w1a, src0);
      u32 b_hi  = (u32)__shfl((int)w1b, src0);
      u32 a_hi2 = (u32)__shfl((int)w1a, src0 + 16);
      u32 b_hi2 = (u32)__shfl((int)w1b, src0 + 16);
      pcA.u[0] = hi ? a_hi : a_lo;
      pcA.u[1] = hi ? b_hi : b_lo;
      pcA.u[2] = hi ? a_hi2 : a_lo2;
      pcA.u[3] = hi ? b_hi2 : b_lo2;
    }
    {
      u32 w0a = (u32)f2bf(p[8])  | ((u32)f2bf(p[9])  << 16);
      u32 w0b = (u32)f2bf(p[10]) | ((u32)f2bf(p[11]) << 16);
      u32 w1a = (u32)f2bf(p[12]) | ((u32)f2bf(p[13]) << 16);
      u32 w1b = (u32)f2bf(p[14]) | ((u32)f2bf(p[15]) << 16);
      u32 a_lo  = (u32)__shfl((int)w0a, src0);
      u32 b_lo  = (u32)__shfl((int)w0b, src0);
      u32 a_lo2 = (u32)__shfl((int)w0a, src0 + 16);
      u32 b_lo2 = (u32)__shfl((int)w0b, src0 + 16);
      u32 a_hi  = (u32)__shfl((int)w1a, src0);
      u32 b_hi  = (u32)__shfl((int)w1b, src0);
      u32 a_hi2 = (u32)__shfl((int)w1a, src0 + 16);
      u32 b_hi2 = (u32)__shfl((int)w1b, src0 + 16);
      pcB.u[0] = hi ? a_hi : a_lo;
      pcB.u[1] = hi ? b_hi : b_lo;
      pcB.u[2] = hi ? a_hi2 : a_lo2;
      pcB.u[3] = hi ? b_hi2 : b_lo2;
    }
    const int vcolA = (g * 16) ^ xr;
    const int vcolB = (64 + g * 16) ^ xr;
    __builtin_amdgcn_s_setprio(1);
#pragma unroll
    for (int j = 0; j < 8; j++) {
      bf16x8 vfA = *(const bf16x8*)(Vl + (j * 16 + q) * 128 + vcolA);
      acc[j] = mfma16(pcA.v, vfA, acc[j]);
    }
#pragma unroll
    for (int j = 0; j < 8; j++) {
      bf16x8 vfB = *(const bf16x8*)(Vl + (j * 16 + q) * 128 + vcolB);
      acc[j] = mfma16(pcB.v, vfB, acc[j]);
    }
    __builtin_amdgcn_s_setprio(0);

    asm volatile("s_waitcnt vmcnt(0)" ::: "memory");
    __syncthreads();
    buf ^= 1;
  }

  float linv = 1.0f / l;
  float linv_r[4];
#pragma unroll
  for (int r = 0; r < 4; r++)
    linv_r[r] = __shfl(linv, (lane & 48) | (g * 4 + r));
  u16* ab = attn + (size_t)(b * S + q0) * 2048 + h * 128;
#pragma unroll
  for (int j = 0; j < 8; j++)
#pragma unroll
    for (int r = 0; r < 4; r++)
      ab[(size_t)(g * 4 + r) * 2048 + j * 16 + q] = f2bf(acc[j][r] * linv_r[r]);
}

// ---------------- launch ----------------
extern "C" void kernel_launch(void* const* d_in, const int* in_sizes, int n_in,
                              void* d_out, int out_size, void* d_ws, size_t ws_size,
                              hipStream_t stream) {
  (void)in_sizes; (void)n_in; (void)out_size; (void)ws_size;
  const int S = 2048;
  const float* x = (const float*)d_in[0];
  const float* qkv = (const float*)d_in[1];
  const float* wk = (const float*)d_in[2];
  const float* wo = (const float*)d_in[3];
  float* out = (float*)d_out;
  float* k_out = out + (size_t)8388608;
  float* v_out = out + (size_t)16777216;

  char* ws = (char*)d_ws;
  // workspace layout (108.0 MB); attn aliases x_bf, k_bf aliases wcomb
  u16* x_bf  = (u16*)(ws + 0);          // 16.78 MB (later: attn_bf)
  u16* wcomb = (u16*)(ws + 16777216);   // 22.02 MB (5376x2048) (later: k_bf)
  u16* wo_bf = (u16*)(ws + 38797312);   // 8.39 MB
  u16* qvk   = (u16*)(ws + 47185920);   // 44.04 MB (4096x5376)
  u16* vt_bf = (u16*)(ws + 91226112);   // 16.78 MB (B,H,128,S)
  u16* attn_bf = x_bf;
  u16* k_bf = wcomb;

  cast_all<<<23040, 256, 0, stream>>>((const float4*)x, (const float4*)qkv, wk,
                                      (const float4*)wo, x_bf, wcomb, wo_bf);

  gemm256<u16, 256><<<dim3(21, 16), 512, 0, stream>>>(x_bf, wcomb, qvk, 4096, 5376, 2048);
  rope_scatter2<<<4096, 256, 0, stream>>>(qvk, k_bf, k_out, S);
  v_scatter<<<8192, 256, 0, stream>>>(qvk, vt_bf, v_out, S);
  flash_attn2<<<1024, 256, 0, stream>>>(qvk, k_bf, vt_bf, attn_bf, S);
  gemm256<float, 128><<<dim3(8, 32), 512, 0, stream>>>(attn_bf, wo_bf, out, 4096, 2048, 2048);
}

// Round 6
// 287.154 us; speedup vs baseline: 2.4982x; 1.0076x over previous
//
#include <hip/hip_runtime.h>
#include <hip/hip_bf16.h>

// Decoupled RoPE MHA on MI355X (gfx950).
// B=2 S=2048 D=2048 H=16 dh=128 nope=64 rope=64
// R6: QVK GEMM BM=128 (672 tiles -> 87.5% round utilization);
// flash: 8-wave/128-row blocks, K dbuf + single V (48KB LDS, 2 blk/CU).

typedef unsigned short u16;
typedef unsigned int u32;
typedef __bf16 bf16x8 __attribute__((ext_vector_type(8)));
typedef float f32x4 __attribute__((ext_vector_type(4)));

__device__ __forceinline__ u16 f2bf(float x) {
  union { __hip_bfloat16 h; u16 u; } c;
  c.h = __float2bfloat16(x);
  return c.u;
}
__device__ __forceinline__ float bf2f(u16 u) {
  union { u32 u; float f; } c;
  c.u = ((u32)u) << 16;
  return c.f;
}
__device__ __forceinline__ f32x4 mfma16(bf16x8 a, bf16x8 b, f32x4 c) {
  return __builtin_amdgcn_mfma_f32_16x16x32_bf16(a, b, c, 0, 0, 0);
}
__device__ __forceinline__ void gload_lds16(const void* g, void* l) {
  __builtin_amdgcn_global_load_lds((__attribute__((address_space(1))) void*)g,
                                   (__attribute__((address_space(3))) void*)l,
                                   16, 0, 0);
}

// ---------------- fused cast kernel ----------------
__global__ __launch_bounds__(256) void cast_all(const float4* __restrict__ x,
                                                const float4* __restrict__ qkv,
                                                const float* __restrict__ wk,
                                                const float4* __restrict__ wo,
                                                u16* __restrict__ x_bf,
                                                u16* __restrict__ wcomb,
                                                u16* __restrict__ wo_bf) {
  int i = blockIdx.x * blockDim.x + threadIdx.x;
  const float4* src;
  u16* dst;
  int j;
  if (i < 2097152) {
    src = x; dst = x_bf; j = i;
  } else if (i < 4194304) {
    src = qkv; dst = wcomb; j = i - 2097152;
  } else if (i < 4849664) {
    j = i - 4194304;  // over 1280x2048/4; rows >=1088 are zero pad
    int r = (j * 4) >> 11;
    u32 lo = 0, hi = 0;
    if (r < 1088) {
      float4 v = ((const float4*)wk)[j];
      lo = (u32)f2bf(v.x) | ((u32)f2bf(v.y) << 16);
      hi = (u32)f2bf(v.z) | ((u32)f2bf(v.w) << 16);
    }
    ((uint2*)(wcomb + 8388608))[j] = make_uint2(lo, hi);
    return;
  } else {
    src = wo; dst = wo_bf; j = i - 4849664;
  }
  float4 v = src[j];
  u32 lo = (u32)f2bf(v.x) | ((u32)f2bf(v.y) << 16);
  u32 hi = (u32)f2bf(v.z) | ((u32)f2bf(v.w) << 16);
  ((uint2*)dst)[j] = make_uint2(lo, hi);
}

// ------------- GEMM BMx256, BK=64, 4 phases/K-tile, templated BM ------------
__device__ __forceinline__ void cstore(u16* C, size_t i, float v) { C[i] = f2bf(v); }
__device__ __forceinline__ void cstore(float* C, size_t i, float v) { C[i] = v; }

template <typename CT, int BM>
__global__ __launch_bounds__(512, 2) void gemm256(const u16* __restrict__ A,
                                                  const u16* __restrict__ W,
                                                  CT* __restrict__ C,
                                                  int M, int N, int K) {
  constexpr int MI = BM / 64;       // a-frags per quadrant (4 or 2)
  constexpr int AH = BM * 64;       // bytes per A half-tile (16K or 8K)
  constexpr int AL = BM / 128;      // gloads/thread per A half (2 or 1)
  constexpr int BOFF = 4 * AH;      // B region base in LDS
  __shared__ char lds[BOFF + 65536];
  const int tid = threadIdx.x;
  const int wid = tid >> 6, lane = tid & 63;
  const int lr = lane & 15, lg = lane >> 4;
  const int wr = wid >> 2, wc = wid & 3;
  const int xorv = (lr & 7) << 4;
  // XCD-aware bijective swizzle (nwg % 8 == 0 at both call sites)
  const int nwg = gridDim.x * gridDim.y;
  const int lin = blockIdx.y * gridDim.x + blockIdx.x;
  const int swz = (lin & 7) * (nwg >> 3) + (lin >> 3);
  const int m0 = (swz / gridDim.x) * BM;
  const int n0 = (swz % gridDim.x) * 256;
  const int nkt = K >> 6;

  f32x4 acc[2 * MI][4] = {};
  bf16x8 a[MI][2], b[4][2];

  // per-thread stage sources (pre-swizzled)
  const int o0 = tid * 16, o1 = 8192 + tid * 16;
  const int r0 = o0 >> 7, c0 = ((o0 & 127) ^ ((r0 & 7) << 4)) >> 1;
  const int r1 = o1 >> 7, c1 = ((o1 & 127) ^ ((r1 & 7) << 4)) >> 1;
  const u16* gA0[2] = {A + (size_t)(m0 + r0) * K + c0,
                       A + (size_t)(m0 + BM / 2 + r0) * K + c0};
  const u16* gA1[2] = {A + (size_t)(m0 + r1) * K + c1,
                       A + (size_t)(m0 + BM / 2 + r1) * K + c1};
  const u16* gB0[2] = {W + (size_t)(n0 + r0) * K + c0,
                       W + (size_t)(n0 + 128 + r0) * K + c0};
  const u16* gB1[2] = {W + (size_t)(n0 + r1) * K + c1,
                       W + (size_t)(n0 + 128 + r1) * K + c1};

  auto STAGEA = [&](int t, int h) {
    char* d_ = lds + (t & 1) * (2 * AH) + h * AH + wid * 1024;
    gload_lds16(gA0[h] + (size_t)t * 64, d_);
    if constexpr (AL == 2) gload_lds16(gA1[h] + (size_t)t * 64, d_ + 8192);
  };
  auto STAGEB = [&](int t, int h) {
    char* d_ = lds + BOFF + (t & 1) * 32768 + h * 16384 + wid * 1024;
    gload_lds16(gB0[h] + (size_t)t * 64, d_);
    gload_lds16(gB1[h] + (size_t)t * 64, d_ + 8192);
  };
  auto WAITKEEP = [&]() {  // keep (t+2)A0+(t+2)B0 in flight
    if constexpr (BM == 256) asm volatile("s_waitcnt vmcnt(4)" ::: "memory");
    else asm volatile("s_waitcnt vmcnt(3)" ::: "memory");
  };

  // prologue
  STAGEA(0, 0); STAGEB(0, 0); STAGEA(0, 1); STAGEB(0, 1);
  if (nkt > 1) { STAGEA(1, 0); STAGEB(1, 0); }
  WAITKEEP();
  __builtin_amdgcn_s_barrier();

  for (int t = 0; t < nkt; ++t) {
    const char* Ab = lds + (t & 1) * (2 * AH);
    const char* Bb = lds + BOFF + (t & 1) * 32768;
    const int arow = wr * (BM / 4), brow = wc * 32;
    // ---- phase 0: (Mh0, Nh0) ----
#pragma unroll
    for (int mi = 0; mi < MI; mi++)
#pragma unroll
      for (int ks = 0; ks < 2; ks++)
        a[mi][ks] = *(const bf16x8*)(Ab + (arow + mi * 16 + lr) * 128 + ((lg * 16 + ks * 64) ^ xorv));
#pragma unroll
    for (int ni = 0; ni < 2; ni++)
#pragma unroll
      for (int ks = 0; ks < 2; ks++)
        b[ni][ks] = *(const bf16x8*)(Bb + (brow + ni * 16 + lr) * 128 + ((lg * 16 + ks * 64) ^ xorv));
    if (t + 1 < nkt) STAGEA(t + 1, 1);
    __builtin_amdgcn_s_barrier();
    asm volatile("s_waitcnt lgkmcnt(0)" ::: "memory");
    __builtin_amdgcn_sched_barrier(0);
    __builtin_amdgcn_s_setprio(1);
#pragma unroll
    for (int mi = 0; mi < MI; mi++)
#pragma unroll
      for (int ni = 0; ni < 2; ni++)
#pragma unroll
        for (int ks = 0; ks < 2; ks++)
          acc[mi][ni] = mfma16(a[mi][ks], b[ni][ks], acc[mi][ni]);
    __builtin_amdgcn_s_setprio(0);
    __builtin_amdgcn_s_barrier();
    // ---- phase 1: (Mh0, Nh1) ----
#pragma unroll
    for (int ni = 0; ni < 2; ni++)
#pragma unroll
      for (int ks = 0; ks < 2; ks++)
        b[2 + ni][ks] = *(const bf16x8*)(Bb + 16384 + (brow + ni * 16 + lr) * 128 + ((lg * 16 + ks * 64) ^ xorv));
    if (t + 1 < nkt) STAGEB(t + 1, 1);
    __builtin_amdgcn_s_barrier();
    asm volatile("s_waitcnt lgkmcnt(0)" ::: "memory");
    __builtin_amdgcn_sched_barrier(0);
    __builtin_amdgcn_s_setprio(1);
#pragma unroll
    for (int mi = 0; mi < MI; mi++)
#pragma unroll
      for (int ni = 0; ni < 2; ni++)
#pragma unroll
        for (int ks = 0; ks < 2; ks++)
          acc[mi][2 + ni] = mfma16(a[mi][ks], b[2 + ni][ks], acc[mi][2 + ni]);
    __builtin_amdgcn_s_setprio(0);
    __builtin_amdgcn_s_barrier();
    // ---- phase 2: (Mh1, Nh0) ----
#pragma unroll
    for (int mi = 0; mi < MI; mi++)
#pragma unroll
      for (int ks = 0; ks < 2; ks++)
        a[mi][ks] = *(const bf16x8*)(Ab + AH + (arow + mi * 16 + lr) * 128 + ((lg * 16 + ks * 64) ^ xorv));
    if (t + 2 < nkt) STAGEA(t + 2, 0);
    __builtin_amdgcn_s_barrier();
    asm volatile("s_waitcnt lgkmcnt(0)" ::: "memory");
    __builtin_amdgcn_sched_barrier(0);
    __builtin_amdgcn_s_setprio(1);
#pragma unroll
    for (int mi = 0; mi < MI; mi++)
#pragma unroll
      for (int ni = 0; ni < 2; ni++)
#pragma unroll
        for (int ks = 0; ks < 2; ks++)
          acc[MI + mi][ni] = mfma16(a[mi][ks], b[ni][ks], acc[MI + mi][ni]);
    __builtin_amdgcn_s_setprio(0);
    __builtin_amdgcn_s_barrier();
    // ---- phase 3: (Mh1, Nh1) ----
    if (t + 2 < nkt) {
      STAGEB(t + 2, 0);
      WAITKEEP();
    } else if (t + 1 < nkt) {
      asm volatile("s_waitcnt vmcnt(0)" ::: "memory");
    }
    __builtin_amdgcn_s_barrier();
    asm volatile("s_waitcnt lgkmcnt(0)" ::: "memory");
    __builtin_amdgcn_sched_barrier(0);
    __builtin_amdgcn_s_setprio(1);
#pragma unroll
    for (int mi = 0; mi < MI; mi++)
#pragma unroll
      for (int ni = 0; ni < 2; ni++)
#pragma unroll
        for (int ks = 0; ks < 2; ks++)
          acc[MI + mi][2 + ni] = mfma16(a[mi][ks], b[2 + ni][ks], acc[MI + mi][2 + ni]);
    __builtin_amdgcn_s_setprio(0);
    __builtin_amdgcn_s_barrier();
  }

  // epilogue
#pragma unroll
  for (int Mh = 0; Mh < 2; Mh++)
#pragma unroll
    for (int mi = 0; mi < MI; mi++) {
      int row = m0 + Mh * (BM / 2) + wr * (BM / 4) + mi * 16 + lg * 4;
#pragma unroll
      for (int Nh = 0; Nh < 2; Nh++)
#pragma unroll
        for (int ni = 0; ni < 2; ni++) {
          int col = n0 + Nh * 128 + wc * 32 + ni * 16 + lr;
#pragma unroll
          for (int r = 0; r < 4; r++)
            cstore(C, (size_t)(row + r) * N + col, acc[Mh * MI + mi][Nh * 2 + ni][r]);
        }
    }
}

// ---------------- RoPE: Q in-place in QVK + K scatter ----------------
__global__ __launch_bounds__(256) void rope_scatter2(u16* __restrict__ QVK,
                                                     u16* __restrict__ kh,
                                                     float* __restrict__ k_out, int S) {
  const int row = blockIdx.x;  // b*S + s
  const int b = row >> 11, s = row & 2047;
  const int tid = threadIdx.x;
  __shared__ float kr[64];
  const float LOG1E4_64 = 0.14391156511f;  // ln(10000)/64
  u16* qrow = QVK + (size_t)row * 5376;
  if (tid < 32) {
    float freq = __expf(-(float)tid * LOG1E4_64);
    float sn, c;
    __sincosf((float)s * freq, &sn, &c);
    float a = bf2f(qrow[5120 + tid]);
    float bb = bf2f(qrow[5152 + tid]);
    kr[tid] = a * c - bb * sn;
    kr[tid + 32] = bb * c + a * sn;
  }
  for (int idx = tid; idx < 512; idx += 256) {
    int h = idx >> 5, jj = idx & 31;
    float freq = __expf(-(float)jj * LOG1E4_64);
    float sn, c;
    __sincosf((float)s * freq, &sn, &c);
    u16* p1 = qrow + h * 128 + 64 + jj;
    u16* p2 = qrow + h * 128 + 96 + jj;
    float x1 = bf2f(*p1), x2 = bf2f(*p2);
    *p1 = f2bf(x1 * c - x2 * sn);
    *p2 = f2bf(x2 * c + x1 * sn);
  }
  __syncthreads();
  for (int idx = tid; idx < 2048; idx += 256) {
    int h = idx >> 7, d = idx & 127;
    float val = (d < 64) ? bf2f(qrow[4096 + h * 64 + d]) : kr[d - 64];
    size_t o = ((size_t)(b * 16 + h) * S + s) * 128 + d;
    kh[o] = f2bf(val);
    k_out[o] = val;
  }
}

// ---------------- V: write v_heads fp32 + transposed Vt (B,H,128,S) ----------
__global__ __launch_bounds__(256) void v_scatter(const u16* __restrict__ QVK,
                                                 u16* __restrict__ vt,
                                                 float* __restrict__ v_out, int S) {
  const int blk = blockIdx.x;
  const int st = blk & 63;
  const int dt = (blk >> 6) & 3;
  const int bh = blk >> 8;
  const int b = bh >> 4, h = bh & 15;
  __shared__ u16 t[32][34];
  const int tx = threadIdx.x & 31, ty = threadIdx.x >> 5;
  const int s0 = st * 32, d0 = dt * 32;
#pragma unroll
  for (int i = 0; i < 4; i++) {
    int sl = ty + 8 * i;
    u16 u = QVK[(size_t)(b * S + s0 + sl) * 5376 + 2048 + h * 128 + d0 + tx];
    t[sl][tx] = u;
    v_out[((size_t)bh * S + s0 + sl) * 128 + d0 + tx] = bf2f(u);
  }
  __syncthreads();
#pragma unroll
  for (int i = 0; i < 4; i++) {
    int dl = ty + 8 * i;
    vt[((size_t)bh * 128 + d0 + dl) * S + s0 + tx] = t[tx][dl];
  }
}

// --------- flash attention v3: 8 waves, 128 q-rows/block, single-V ----------
// LDS: K0 [0,16K) | K1 [16K,32K) | V [32K,48K). 2 blocks/CU (16 waves).
// Per tile: stage K(t+1); waitK+bar; QK+softmax; waitV+bar; PV; bar; stage V(t+1).
// Per-wave vmcnt (2 loads per K-stage, 2 per V-stage), derived from issue order:
// steady: waitK=vmcnt(4) [leaves V(t),K(t+1)], waitV=vmcnt(2) [leaves K(t+1)];
// last tile: waitK=vmcnt(2), waitV=vmcnt(0).
__global__ __launch_bounds__(512) void flash_attn3(const u16* __restrict__ QVK,
                                                   const u16* __restrict__ Kh,
                                                   const u16* __restrict__ Vt,
                                                   u16* __restrict__ attn, int S) {
  __shared__ char lds[49152];
  const int tid = threadIdx.x, wid = tid >> 6, lane = tid & 63;
  const int bh = blockIdx.x & 31;
  const int qb = 15 - (int)(blockIdx.x >> 5);  // longest blocks first
  const int q0 = qb * 128 + wid * 16;
  const int b = bh >> 4, h = bh & 15;
  const int q = lane & 15, g = lane >> 4;
  const u16* Qb = QVK + (size_t)b * S * 5376 + h * 128;
  const u16* Kb = Kh + (size_t)bh * S * 128;
  const u16* Vb = Vt + (size_t)bh * 128 * S;
  const int qg = q0 + q;
  const int xr = (q & 7) << 4;

  // per-lane pre-swizzled stage sources; 8 waves x 2 slots of 1KB each
  const u16* srcK[2];
  const u16* srcV[2];
#pragma unroll
  for (int i = 0; i < 2; i++) {
    int o = ((i * 8 + wid) << 10) | (lane << 4);
    int rK = o >> 8, cbK = (o & 255) ^ ((rK & 7) << 4);
    srcK[i] = Kb + rK * 128 + (cbK >> 1);
    int dV = o >> 7, kbV = (o & 127) ^ ((dV & 7) << 4);
    srcV[i] = Vb + (size_t)dV * S + (kbV >> 1);
  }

  bf16x8 qf[4];
#pragma unroll
  for (int f = 0; f < 4; f++)
    qf[f] = *(const bf16x8*)(Qb + (size_t)qg * 5376 + f * 32 + g * 8);

  f32x4 acc[8] = {};
  float m = -INFINITY, l = 0.f;
  const float sc = 0.08838834764831845f;  // 1/sqrt(128)
  const int ktiles = 2 * qb + 2;

  // prologue: K(0)->buf0, V(0)->Vbuf
#pragma unroll
  for (int i = 0; i < 2; i++) {
    char* ld = lds + ((i * 8 + wid) << 10);
    gload_lds16(srcK[i], ld);
    gload_lds16(srcV[i], ld + 32768);
  }
  asm volatile("s_waitcnt vmcnt(0)" ::: "memory");
  __builtin_amdgcn_s_barrier();

  for (int kt = 0; kt < ktiles; ++kt) {
    const char* Kt = lds + (kt & 1) * 16384;
    const char* Vl = lds + 32768;
    const bool more = (kt + 1 < ktiles);
    if (more) {
#pragma unroll
      for (int i = 0; i < 2; i++)
        gload_lds16(srcK[i] + (size_t)(kt + 1) * 8192,
                    lds + (((kt & 1) ^ 1) << 14) + ((i * 8 + wid) << 10));
      asm volatile("s_waitcnt vmcnt(4)" ::: "memory");
    } else {
      asm volatile("s_waitcnt vmcnt(2)" ::: "memory");
    }
    __builtin_amdgcn_s_barrier();

    // ---- QK^T for 64 keys: s[c] holds keys kbg + c*16 + g*4 + r ----
    f32x4 s[4] = {};
    const char* Kq = Kt + q * 256;
    __builtin_amdgcn_s_setprio(1);
#pragma unroll
    for (int f = 0; f < 4; f++) {
#pragma unroll
      for (int c = 0; c < 4; c++) {
        bf16x8 kf = *(const bf16x8*)(Kq + c * 4096 + ((f * 64 + g * 16) ^ xr));
        s[c] = mfma16(kf, qf[f], s[c]);
      }
    }
    __builtin_amdgcn_s_setprio(0);

    const int kbg = kt * 64;
    float v[16];
    const bool maskt = (kbg + 63 > q0);
#pragma unroll
    for (int c = 0; c < 4; c++)
#pragma unroll
      for (int r = 0; r < 4; r++) {
        float x = s[c][r];
        if (maskt && (kbg + c * 16 + g * 4 + r > qg)) x = -1e30f;
        v[c * 4 + r] = x;
      }
    float tm = v[0];
#pragma unroll
    for (int i = 1; i < 16; i++) tm = fmaxf(tm, v[i]);
    tm = fmaxf(tm, __shfl_xor(tm, 16));
    tm = fmaxf(tm, __shfl_xor(tm, 32));
    // defer-max: only rescale when raw max grew by > 64 (5.7 nats scaled)
    if (!__all(tm <= m + 64.0f)) {
      float mnew = fmaxf(m, tm);
      float corr = __expf((m - mnew) * sc);
      m = mnew;
      l *= corr;
      float corr_r[4];
#pragma unroll
      for (int r = 0; r < 4; r++)
        corr_r[r] = __shfl(corr, (lane & 48) | (g * 4 + r));
#pragma unroll
      for (int j = 0; j < 8; j++)
#pragma unroll
        for (int r = 0; r < 4; r++) acc[j][r] *= corr_r[r];
    }
    const float nms = -m * sc;
    float p[16], ts = 0.f;
#pragma unroll
    for (int i = 0; i < 16; i++) {
      p[i] = __expf(fmaf(v[i], sc, nms));
      ts += p[i];
    }
    ts += __shfl_xor(ts, 16);
    ts += __shfl_xor(ts, 32);
    l += ts;

    // P redistribution: dst lane (g,q) needs keys [g*8,g*8+8) (+32 for pcB)
    const int src0 = q | ((g & 1) << 5);
    const bool hi = (g & 2);
    union { u32 u[4]; bf16x8 v; } pcA, pcB;
    {
      u32 w0a = (u32)f2bf(p[0]) | ((u32)f2bf(p[1]) << 16);
      u32 w0b = (u32)f2bf(p[2]) | ((u32)f2bf(p[3]) << 16);
      u32 w1a = (u32)f2bf(p[4]) | ((u32)f2bf(p[5]) << 16);
      u32 w1b = (u32)f2bf(p[6]) | ((u32)f2bf(p[7]) << 16);
      u32 a_lo  = (u32)__shfl((int)w0a, src0);
      u32 b_lo  = (u32)__shfl((int)w0b, src0);
      u32 a_lo2 = (u32)__shfl((int)w0a, src0 + 16);
      u32 b_lo2 = (u32)__shfl((int)w0b, src0 + 16);
      u32 a_hi  = (u32)__shfl((int)w1a, src0);
      u32 b_hi  = (u32)__shfl((int)w1b, src0);
      u32 a_hi2 = (u32)__shfl((int)w1a, src0 + 16);
      u32 b_hi2 = (u32)__shfl((int)w1b, src0 + 16);
      pcA.u[0] = hi ? a_hi : a_lo;
      pcA.u[1] = hi ? b_hi : b_lo;
      pcA.u[2] = hi ? a_hi2 : a_lo2;
      pcA.u[3] = hi ? b_hi2 : b_lo2;
    }
    {
      u32 w0a = (u32)f2bf(p[8])  | ((u32)f2bf(p[9])  << 16);
      u32 w0b = (u32)f2bf(p[10]) | ((u32)f2bf(p[11]) << 16);
      u32 w1a = (u32)f2bf(p[12]) | ((u32)f2bf(p[13]) << 16);
      u32 w1b = (u32)f2bf(p[14]) | ((u32)f2bf(p[15]) << 16);
      u32 a_lo  = (u32)__shfl((int)w0a, src0);
      u32 b_lo  = (u32)__shfl((int)w0b, src0);
      u32 a_lo2 = (u32)__shfl((int)w0a, src0 + 16);
      u32 b_lo2 = (u32)__shfl((int)w0b, src0 + 16);
      u32 a_hi  = (u32)__shfl((int)w1a, src0);
      u32 b_hi  = (u32)__shfl((int)w1b, src0);
      u32 a_hi2 = (u32)__shfl((int)w1a, src0 + 16);
      u32 b_hi2 = (u32)__shfl((int)w1b, src0 + 16);
      pcB.u[0] = hi ? a_hi : a_lo;
      pcB.u[1] = hi ? b_hi : b_lo;
      pcB.u[2] = hi ? a_hi2 : a_lo2;
      pcB.u[3] = hi ? b_hi2 : b_lo2;
    }

    if (more) asm volatile("s_waitcnt vmcnt(2)" ::: "memory");
    else      asm volatile("s_waitcnt vmcnt(0)" ::: "memory");
    __builtin_amdgcn_s_barrier();

    const int vcolA = (g * 16) ^ xr;
    const int vcolB = (64 + g * 16) ^ xr;
    __builtin_amdgcn_s_setprio(1);
#pragma unroll
    for (int j = 0; j < 8; j++) {
      bf16x8 vfA = *(const bf16x8*)(Vl + (j * 16 + q) * 128 + vcolA);
      acc[j] = mfma16(pcA.v, vfA, acc[j]);
    }
#pragma unroll
    for (int j = 0; j < 8; j++) {
      bf16x8 vfB = *(const bf16x8*)(Vl + (j * 16 + q) * 128 + vcolB);
      acc[j] = mfma16(pcB.v, vfB, acc[j]);
    }
    __builtin_amdgcn_s_setprio(0);

    __builtin_amdgcn_s_barrier();  // V free for overwrite
    if (more) {
#pragma unroll
      for (int i = 0; i < 2; i++)
        gload_lds16(srcV[i] + (size_t)(kt + 1) * 64,
                    lds + 32768 + ((i * 8 + wid) << 10));
    }
  }

  float linv = 1.0f / l;
  float linv_r[4];
#pragma unroll
  for (int r = 0; r < 4; r++)
    linv_r[r] = __shfl(linv, (lane & 48) | (g * 4 + r));
  u16* ab = attn + (size_t)(b * S + q0) * 2048 + h * 128;
#pragma unroll
  for (int j = 0; j < 8; j++)
#pragma unroll
    for (int r = 0; r < 4; r++)
      ab[(size_t)(g * 4 + r) * 2048 + j * 16 + q] = f2bf(acc[j][r] * linv_r[r]);
}

// ---------------- launch ----------------
extern "C" void kernel_launch(void* const* d_in, const int* in_sizes, int n_in,
                              void* d_out, int out_size, void* d_ws, size_t ws_size,
                              hipStream_t stream) {
  (void)in_sizes; (void)n_in; (void)out_size; (void)ws_size;
  const int S = 2048;
  const float* x = (const float*)d_in[0];
  const float* qkv = (const float*)d_in[1];
  const float* wk = (const float*)d_in[2];
  const float* wo = (const float*)d_in[3];
  float* out = (float*)d_out;
  float* k_out = out + (size_t)8388608;
  float* v_out = out + (size_t)16777216;

  char* ws = (char*)d_ws;
  // workspace layout (108.0 MB); attn aliases x_bf, k_bf aliases wcomb
  u16* x_bf  = (u16*)(ws + 0);          // 16.78 MB (later: attn_bf)
  u16* wcomb = (u16*)(ws + 16777216);   // 22.02 MB (5376x2048) (later: k_bf)
  u16* wo_bf = (u16*)(ws + 38797312);   // 8.39 MB
  u16* qvk   = (u16*)(ws + 47185920);   // 44.04 MB (4096x5376)
  u16* vt_bf = (u16*)(ws + 91226112);   // 16.78 MB (B,H,128,S)
  u16* attn_bf = x_bf;
  u16* k_bf = wcomb;

  cast_all<<<23040, 256, 0, stream>>>((const float4*)x, (const float4*)qkv, wk,
                                      (const float4*)wo, x_bf, wcomb, wo_bf);

  gemm256<u16, 128><<<dim3(21, 32), 512, 0, stream>>>(x_bf, wcomb, qvk, 4096, 5376, 2048);
  rope_scatter2<<<4096, 256, 0, stream>>>(qvk, k_bf, k_out, S);
  v_scatter<<<8192, 256, 0, stream>>>(qvk, vt_bf, v_out, S);
  flash_attn3<<<512, 512, 0, stream>>>(qvk, k_bf, vt_bf, attn_bf, S);
  gemm256<float, 128><<<dim3(8, 32), 512, 0, stream>>>(attn_bf, wo_bf, out, 4096, 2048, 2048);
}

// Round 7
// 279.648 us; speedup vs baseline: 2.5653x; 1.0268x over previous
//
#include <hip/hip_runtime.h>
#include <hip/hip_bf16.h>

// Decoupled RoPE MHA on MI355X (gfx950).
// B=2 S=2048 D=2048 H=16 dh=128 nope=64 rope=64
// R7: QVK GEMM split into Q+V (256x256, grid 16x16 = 1 perfect round) and
// K (256x128, grid 10x16); gemm256 templated on (BM,BN). Flash: P
// redistribution via per-wave LDS roundtrip instead of 16 ds_bpermute.

typedef unsigned short u16;
typedef unsigned int u32;
typedef __bf16 bf16x8 __attribute__((ext_vector_type(8)));
typedef float f32x4 __attribute__((ext_vector_type(4)));

__device__ __forceinline__ u16 f2bf(float x) {
  union { __hip_bfloat16 h; u16 u; } c;
  c.h = __float2bfloat16(x);
  return c.u;
}
__device__ __forceinline__ float bf2f(u16 u) {
  union { u32 u; float f; } c;
  c.u = ((u32)u) << 16;
  return c.f;
}
__device__ __forceinline__ u32 pack2(float a, float b) {
  return (u32)f2bf(a) | ((u32)f2bf(b) << 16);
}
__device__ __forceinline__ f32x4 mfma16(bf16x8 a, bf16x8 b, f32x4 c) {
  return __builtin_amdgcn_mfma_f32_16x16x32_bf16(a, b, c, 0, 0, 0);
}
__device__ __forceinline__ void gload_lds16(const void* g, void* l) {
  __builtin_amdgcn_global_load_lds((__attribute__((address_space(1))) void*)g,
                                   (__attribute__((address_space(3))) void*)l,
                                   16, 0, 0);
}

// ---------------- fused cast kernel ----------------
__global__ __launch_bounds__(256) void cast_all(const float4* __restrict__ x,
                                                const float4* __restrict__ qkv,
                                                const float* __restrict__ wk,
                                                const float4* __restrict__ wo,
                                                u16* __restrict__ x_bf,
                                                u16* __restrict__ wcomb,
                                                u16* __restrict__ wo_bf) {
  int i = blockIdx.x * blockDim.x + threadIdx.x;
  const float4* src;
  u16* dst;
  int j;
  if (i < 2097152) {
    src = x; dst = x_bf; j = i;
  } else if (i < 4194304) {
    src = qkv; dst = wcomb; j = i - 2097152;
  } else if (i < 4849664) {
    j = i - 4194304;  // over 1280x2048/4; rows >=1088 are zero pad
    int r = (j * 4) >> 11;
    u32 lo = 0, hi = 0;
    if (r < 1088) {
      float4 v = ((const float4*)wk)[j];
      lo = pack2(v.x, v.y);
      hi = pack2(v.z, v.w);
    }
    ((uint2*)(wcomb + 8388608))[j] = make_uint2(lo, hi);
    return;
  } else {
    src = wo; dst = wo_bf; j = i - 4849664;
  }
  float4 v = src[j];
  ((uint2*)dst)[j] = make_uint2(pack2(v.x, v.y), pack2(v.z, v.w));
}

// ------------- GEMM BMxBN, BK=64, 4 phases/K-tile, templated (BM,BN) --------
// C[M,Nld] = A[M,K] @ W[N,K]^T (N extent from grid; N param = leading dim).
// 8 waves (2M x 4N), 512 thr, double-buffered LDS, T2 swizzle via
// pre-swizzled global source, counted vmcnt, T5 setprio.
__device__ __forceinline__ void cstore(u16* C, size_t i, float v) { C[i] = f2bf(v); }
__device__ __forceinline__ void cstore(float* C, size_t i, float v) { C[i] = v; }

template <typename CT, int BM, int BN>
__global__ __launch_bounds__(512, 2) void gemm256(const u16* __restrict__ A,
                                                  const u16* __restrict__ W,
                                                  CT* __restrict__ C,
                                                  int M, int N, int K) {
  constexpr int MI = BM / 64;   // a-frags per phase
  constexpr int NI = BN / 128;  // b-frags per phase
  constexpr int AH = BM * 64;   // bytes per A half-tile
  constexpr int BH = BN * 64;   // bytes per B half-tile
  constexpr int AL = BM / 128;  // gloads/thread per A half
  constexpr int BL = BN / 128;  // gloads/thread per B half
  constexpr int BOFF = 4 * AH;  // B region base in LDS
  __shared__ char lds[BOFF + 4 * BH];
  const int tid = threadIdx.x;
  const int wid = tid >> 6, lane = tid & 63;
  const int lr = lane & 15, lg = lane >> 4;
  const int wr = wid >> 2, wc = wid & 3;
  const int xorv = (lr & 7) << 4;
  // XCD-aware bijective swizzle (nwg % 8 == 0 at all call sites)
  const int nwg = gridDim.x * gridDim.y;
  const int lin = blockIdx.y * gridDim.x + blockIdx.x;
  const int swz = (lin & 7) * (nwg >> 3) + (lin >> 3);
  const int m0 = (swz / gridDim.x) * BM;
  const int n0 = (swz % gridDim.x) * BN;
  const int nkt = K >> 6;

  f32x4 acc[2 * MI][2 * NI] = {};
  bf16x8 a[MI][2], b[2 * NI][2];

  // per-thread stage sources (pre-swizzled)
  const int o0 = tid * 16, o1 = 8192 + tid * 16;
  const int r0 = o0 >> 7, c0 = ((o0 & 127) ^ ((r0 & 7) << 4)) >> 1;
  const int r1 = o1 >> 7, c1 = ((o1 & 127) ^ ((r1 & 7) << 4)) >> 1;
  const u16* gA0[2] = {A + (size_t)(m0 + r0) * K + c0,
                       A + (size_t)(m0 + BM / 2 + r0) * K + c0};
  const u16* gA1[2] = {A + (size_t)(m0 + r1) * K + c1,
                       A + (size_t)(m0 + BM / 2 + r1) * K + c1};
  const u16* gB0[2] = {W + (size_t)(n0 + r0) * K + c0,
                       W + (size_t)(n0 + BN / 2 + r0) * K + c0};
  const u16* gB1[2] = {W + (size_t)(n0 + r1) * K + c1,
                       W + (size_t)(n0 + BN / 2 + r1) * K + c1};

  auto STAGEA = [&](int t, int h) {
    char* d_ = lds + (t & 1) * (2 * AH) + h * AH + wid * 1024;
    gload_lds16(gA0[h] + (size_t)t * 64, d_);
    if constexpr (AL == 2) gload_lds16(gA1[h] + (size_t)t * 64, d_ + 8192);
  };
  auto STAGEB = [&](int t, int h) {
    char* d_ = lds + BOFF + (t & 1) * (2 * BH) + h * BH + wid * 1024;
    gload_lds16(gB0[h] + (size_t)t * 64, d_);
    if constexpr (BL == 2) gload_lds16(gB1[h] + (size_t)t * 64, d_ + 8192);
  };
  auto WAITKEEP = [&]() {  // keep (t+2)A0+(t+2)B0 in flight = AL+BL loads
    if constexpr (AL + BL == 4) asm volatile("s_waitcnt vmcnt(4)" ::: "memory");
    else asm volatile("s_waitcnt vmcnt(3)" ::: "memory");
  };

  // prologue
  STAGEA(0, 0); STAGEB(0, 0); STAGEA(0, 1); STAGEB(0, 1);
  if (nkt > 1) { STAGEA(1, 0); STAGEB(1, 0); }
  WAITKEEP();
  __builtin_amdgcn_s_barrier();

  for (int t = 0; t < nkt; ++t) {
    const char* Ab = lds + (t & 1) * (2 * AH);
    const char* Bb = lds + BOFF + (t & 1) * (2 * BH);
    const int arow = wr * (BM / 4), brow = wc * (BN / 8);
    // ---- phase 0: (Mh0, Nh0) ----
#pragma unroll
    for (int mi = 0; mi < MI; mi++)
#pragma unroll
      for (int ks = 0; ks < 2; ks++)
        a[mi][ks] = *(const bf16x8*)(Ab + (arow + mi * 16 + lr) * 128 + ((lg * 16 + ks * 64) ^ xorv));
#pragma unroll
    for (int ni = 0; ni < NI; ni++)
#pragma unroll
      for (int ks = 0; ks < 2; ks++)
        b[ni][ks] = *(const bf16x8*)(Bb + (brow + ni * 16 + lr) * 128 + ((lg * 16 + ks * 64) ^ xorv));
    if (t + 1 < nkt) STAGEA(t + 1, 1);
    __builtin_amdgcn_s_barrier();
    asm volatile("s_waitcnt lgkmcnt(0)" ::: "memory");
    __builtin_amdgcn_sched_barrier(0);
    __builtin_amdgcn_s_setprio(1);
#pragma unroll
    for (int mi = 0; mi < MI; mi++)
#pragma unroll
      for (int ni = 0; ni < NI; ni++)
#pragma unroll
        for (int ks = 0; ks < 2; ks++)
          acc[mi][ni] = mfma16(a[mi][ks], b[ni][ks], acc[mi][ni]);
    __builtin_amdgcn_s_setprio(0);
    __builtin_amdgcn_s_barrier();
    // ---- phase 1: (Mh0, Nh1) ----
#pragma unroll
    for (int ni = 0; ni < NI; ni++)
#pragma unroll
      for (int ks = 0; ks < 2; ks++)
        b[NI + ni][ks] = *(const bf16x8*)(Bb + BH + (brow + ni * 16 + lr) * 128 + ((lg * 16 + ks * 64) ^ xorv));
    if (t + 1 < nkt) STAGEB(t + 1, 1);
    __builtin_amdgcn_s_barrier();
    asm volatile("s_waitcnt lgkmcnt(0)" ::: "memory");
    __builtin_amdgcn_sched_barrier(0);
    __builtin_amdgcn_s_setprio(1);
#pragma unroll
    for (int mi = 0; mi < MI; mi++)
#pragma unroll
      for (int ni = 0; ni < NI; ni++)
#pragma unroll
        for (int ks = 0; ks < 2; ks++)
          acc[mi][NI + ni] = mfma16(a[mi][ks], b[NI + ni][ks], acc[mi][NI + ni]);
    __builtin_amdgcn_s_setprio(0);
    __builtin_amdgcn_s_barrier();
    // ---- phase 2: (Mh1, Nh0) ----
#pragma unroll
    for (int mi = 0; mi < MI; mi++)
#pragma unroll
      for (int ks = 0; ks < 2; ks++)
        a[mi][ks] = *(const bf16x8*)(Ab + AH + (arow + mi * 16 + lr) * 128 + ((lg * 16 + ks * 64) ^ xorv));
    if (t + 2 < nkt) STAGEA(t + 2, 0);
    __builtin_amdgcn_s_barrier();
    asm volatile("s_waitcnt lgkmcnt(0)" ::: "memory");
    __builtin_amdgcn_sched_barrier(0);
    __builtin_amdgcn_s_setprio(1);
#pragma unroll
    for (int mi = 0; mi < MI; mi++)
#pragma unroll
      for (int ni = 0; ni < NI; ni++)
#pragma unroll
        for (int ks = 0; ks < 2; ks++)
          acc[MI + mi][ni] = mfma16(a[mi][ks], b[ni][ks], acc[MI + mi][ni]);
    __builtin_amdgcn_s_setprio(0);
    __builtin_amdgcn_s_barrier();
    // ---- phase 3: (Mh1, Nh1) ----
    if (t + 2 < nkt) {
      STAGEB(t + 2, 0);
      WAITKEEP();
    } else if (t + 1 < nkt) {
      asm volatile("s_waitcnt vmcnt(0)" ::: "memory");
    }
    __builtin_amdgcn_s_barrier();
    asm volatile("s_waitcnt lgkmcnt(0)" ::: "memory");
    __builtin_amdgcn_sched_barrier(0);
    __builtin_amdgcn_s_setprio(1);
#pragma unroll
    for (int mi = 0; mi < MI; mi++)
#pragma unroll
      for (int ni = 0; ni < NI; ni++)
#pragma unroll
        for (int ks = 0; ks < 2; ks++)
          acc[MI + mi][NI + ni] = mfma16(a[mi][ks], b[NI + ni][ks], acc[MI + mi][NI + ni]);
    __builtin_amdgcn_s_setprio(0);
    __builtin_amdgcn_s_barrier();
  }

  // epilogue
#pragma unroll
  for (int Mh = 0; Mh < 2; Mh++)
#pragma unroll
    for (int mi = 0; mi < MI; mi++) {
      int row = m0 + Mh * (BM / 2) + wr * (BM / 4) + mi * 16 + lg * 4;
#pragma unroll
      for (int Nh = 0; Nh < 2; Nh++)
#pragma unroll
        for (int ni = 0; ni < NI; ni++) {
          int col = n0 + Nh * (BN / 2) + wc * (BN / 8) + ni * 16 + lr;
#pragma unroll
          for (int r = 0; r < 4; r++)
            cstore(C, (size_t)(row + r) * N + col, acc[Mh * MI + mi][Nh * NI + ni][r]);
        }
    }
}

// ---------------- RoPE: Q in-place in QVK + K scatter ----------------
__global__ __launch_bounds__(256) void rope_scatter2(u16* __restrict__ QVK,
                                                     u16* __restrict__ kh,
                                                     float* __restrict__ k_out, int S) {
  const int row = blockIdx.x;  // b*S + s
  const int b = row >> 11, s = row & 2047;
  const int tid = threadIdx.x;
  __shared__ float kr[64];
  const float LOG1E4_64 = 0.14391156511f;  // ln(10000)/64
  u16* qrow = QVK + (size_t)row * 5376;
  if (tid < 32) {
    float freq = __expf(-(float)tid * LOG1E4_64);
    float sn, c;
    __sincosf((float)s * freq, &sn, &c);
    float a = bf2f(qrow[5120 + tid]);
    float bb = bf2f(qrow[5152 + tid]);
    kr[tid] = a * c - bb * sn;
    kr[tid + 32] = bb * c + a * sn;
  }
  for (int idx = tid; idx < 512; idx += 256) {
    int h = idx >> 5, jj = idx & 31;
    float freq = __expf(-(float)jj * LOG1E4_64);
    float sn, c;
    __sincosf((float)s * freq, &sn, &c);
    u16* p1 = qrow + h * 128 + 64 + jj;
    u16* p2 = qrow + h * 128 + 96 + jj;
    float x1 = bf2f(*p1), x2 = bf2f(*p2);
    *p1 = f2bf(x1 * c - x2 * sn);
    *p2 = f2bf(x2 * c + x1 * sn);
  }
  __syncthreads();
  for (int idx = tid; idx < 2048; idx += 256) {
    int h = idx >> 7, d = idx & 127;
    float val = (d < 64) ? bf2f(qrow[4096 + h * 64 + d]) : kr[d - 64];
    size_t o = ((size_t)(b * 16 + h) * S + s) * 128 + d;
    kh[o] = f2bf(val);
    k_out[o] = val;
  }
}

// ---------------- V: write v_heads fp32 + transposed Vt (B,H,128,S) ----------
__global__ __launch_bounds__(256) void v_scatter(const u16* __restrict__ QVK,
                                                 u16* __restrict__ vt,
                                                 float* __restrict__ v_out, int S) {
  const int blk = blockIdx.x;
  const int st = blk & 63;
  const int dt = (blk >> 6) & 3;
  const int bh = blk >> 8;
  const int b = bh >> 4, h = bh & 15;
  __shared__ u16 t[32][34];
  const int tx = threadIdx.x & 31, ty = threadIdx.x >> 5;
  const int s0 = st * 32, d0 = dt * 32;
#pragma unroll
  for (int i = 0; i < 4; i++) {
    int sl = ty + 8 * i;
    u16 u = QVK[(size_t)(b * S + s0 + sl) * 5376 + 2048 + h * 128 + d0 + tx];
    t[sl][tx] = u;
    v_out[((size_t)bh * S + s0 + sl) * 128 + d0 + tx] = bf2f(u);
  }
  __syncthreads();
#pragma unroll
  for (int i = 0; i < 4; i++) {
    int dl = ty + 8 * i;
    vt[((size_t)bh * 128 + d0 + dl) * S + s0 + tx] = t[tx][dl];
  }
}

// --------- flash attention v4: 8 waves, 128 q-rows/block, LDS P-exchange ----
// LDS: K0 [0,16K) | K1 [16K,32K) | V [32K,48K) | P [48K, 48K+8*2304).
// P region: per-wave 16 rows x 144B (row q = P[q][key] bf16, XOR-swizzled
// byte ^= ((q&7)<<4), stride 144B rotates banks by 4q). Replaces 16
// ds_bpermute with 4 ds_write_b64 + 2 ds_read_b128 per tile (wave-local,
// no barrier needed).
__global__ __launch_bounds__(512) void flash_attn4(const u16* __restrict__ QVK,
                                                   const u16* __restrict__ Kh,
                                                   const u16* __restrict__ Vt,
                                                   u16* __restrict__ attn, int S) {
  __shared__ char lds[49152 + 8 * 2304];
  const int tid = threadIdx.x, wid = tid >> 6, lane = tid & 63;
  const int bh = blockIdx.x & 31;
  const int qb = 15 - (int)(blockIdx.x >> 5);  // longest blocks first
  const int q0 = qb * 128 + wid * 16;
  const int b = bh >> 4, h = bh & 15;
  const int q = lane & 15, g = lane >> 4;
  const u16* Qb = QVK + (size_t)b * S * 5376 + h * 128;
  const u16* Kb = Kh + (size_t)bh * S * 128;
  const u16* Vb = Vt + (size_t)bh * 128 * S;
  const int qg = q0 + q;
  const int xr = (q & 7) << 4;
  char* const Pw = lds + 49152 + wid * 2304 + q * 144;  // this lane's P row

  // per-lane pre-swizzled stage sources; 8 waves x 2 slots of 1KB each
  const u16* srcK[2];
  const u16* srcV[2];
#pragma unroll
  for (int i = 0; i < 2; i++) {
    int o = ((i * 8 + wid) << 10) | (lane << 4);
    int rK = o >> 8, cbK = (o & 255) ^ ((rK & 7) << 4);
    srcK[i] = Kb + rK * 128 + (cbK >> 1);
    int dV = o >> 7, kbV = (o & 127) ^ ((dV & 7) << 4);
    srcV[i] = Vb + (size_t)dV * S + (kbV >> 1);
  }

  bf16x8 qf[4];
#pragma unroll
  for (int f = 0; f < 4; f++)
    qf[f] = *(const bf16x8*)(Qb + (size_t)qg * 5376 + f * 32 + g * 8);

  f32x4 acc[8] = {};
  float m = -INFINITY, l = 0.f;
  const float sc = 0.08838834764831845f;  // 1/sqrt(128)
  const int ktiles = 2 * qb + 2;

  // prologue: K(0)->buf0, V(0)->Vbuf
#pragma unroll
  for (int i = 0; i < 2; i++) {
    char* ld = lds + ((i * 8 + wid) << 10);
    gload_lds16(srcK[i], ld);
    gload_lds16(srcV[i], ld + 32768);
  }
  asm volatile("s_waitcnt vmcnt(0)" ::: "memory");
  __builtin_amdgcn_s_barrier();

  for (int kt = 0; kt < ktiles; ++kt) {
    const char* Kt = lds + (kt & 1) * 16384;
    const char* Vl = lds + 32768;
    const bool more = (kt + 1 < ktiles);
    if (more) {
#pragma unroll
      for (int i = 0; i < 2; i++)
        gload_lds16(srcK[i] + (size_t)(kt + 1) * 8192,
                    lds + (((kt & 1) ^ 1) << 14) + ((i * 8 + wid) << 10));
      asm volatile("s_waitcnt vmcnt(4)" ::: "memory");
    } else {
      asm volatile("s_waitcnt vmcnt(2)" ::: "memory");
    }
    __builtin_amdgcn_s_barrier();

    // ---- QK^T for 64 keys: s[c] holds keys kbg + c*16 + g*4 + r ----
    f32x4 s[4] = {};
    const char* Kq = Kt + q * 256;
    __builtin_amdgcn_s_setprio(1);
#pragma unroll
    for (int f = 0; f < 4; f++) {
#pragma unroll
      for (int c = 0; c < 4; c++) {
        bf16x8 kf = *(const bf16x8*)(Kq + c * 4096 + ((f * 64 + g * 16) ^ xr));
        s[c] = mfma16(kf, qf[f], s[c]);
      }
    }
    __builtin_amdgcn_s_setprio(0);

    const int kbg = kt * 64;
    float v[16];
    const bool maskt = (kbg + 63 > q0);
#pragma unroll
    for (int c = 0; c < 4; c++)
#pragma unroll
      for (int r = 0; r < 4; r++) {
        float x = s[c][r];
        if (maskt && (kbg + c * 16 + g * 4 + r > qg)) x = -1e30f;
        v[c * 4 + r] = x;
      }
    float tm = v[0];
#pragma unroll
    for (int i = 1; i < 16; i++) tm = fmaxf(tm, v[i]);
    tm = fmaxf(tm, __shfl_xor(tm, 16));
    tm = fmaxf(tm, __shfl_xor(tm, 32));
    // defer-max: only rescale when raw max grew by > 64 (5.7 nats scaled)
    if (!__all(tm <= m + 64.0f)) {
      float mnew = fmaxf(m, tm);
      float corr = __expf((m - mnew) * sc);
      m = mnew;
      l *= corr;
      float corr_r[4];
#pragma unroll
      for (int r = 0; r < 4; r++)
        corr_r[r] = __shfl(corr, (lane & 48) | (g * 4 + r));
#pragma unroll
      for (int j = 0; j < 8; j++)
#pragma unroll
        for (int r = 0; r < 4; r++) acc[j][r] *= corr_r[r];
    }
    const float nms = -m * sc;
    float p[16], ts = 0.f;
#pragma unroll
    for (int i = 0; i < 16; i++) {
      p[i] = __expf(fmaf(v[i], sc, nms));
      ts += p[i];
    }
    ts += __shfl_xor(ts, 16);
    ts += __shfl_xor(ts, 32);
    l += ts;

    // P exchange via wave-local LDS: lane (g,q) writes keys c*16+g*4+[0,4)
    // of row q at logical byte c*32+g*8 (^swizzle); reads back its A-frags
    // (keys g*8..g*8+7 and 32+g*8..32+g*8+7) as two b128.
#pragma unroll
    for (int c = 0; c < 4; c++) {
      int off = (c * 32 + g * 8) ^ xr;
      *(uint2*)(Pw + off) = make_uint2(pack2(p[c * 4], p[c * 4 + 1]),
                                       pack2(p[c * 4 + 2], p[c * 4 + 3]));
    }
    asm volatile("s_waitcnt lgkmcnt(0)" ::: "memory");
    __builtin_amdgcn_sched_barrier(0);
    bf16x8 pcA = *(const bf16x8*)(Pw + ((g * 16) ^ xr));
    bf16x8 pcB = *(const bf16x8*)(Pw + ((64 + g * 16) ^ xr));

    if (more) asm volatile("s_waitcnt vmcnt(2)" ::: "memory");
    else      asm volatile("s_waitcnt vmcnt(0)" ::: "memory");
    __builtin_amdgcn_s_barrier();

    const int vcolA = (g * 16) ^ xr;
    const int vcolB = (64 + g * 16) ^ xr;
    __builtin_amdgcn_s_setprio(1);
#pragma unroll
    for (int j = 0; j < 8; j++) {
      bf16x8 vfA = *(const bf16x8*)(Vl + (j * 16 + q) * 128 + vcolA);
      acc[j] = mfma16(pcA, vfA, acc[j]);
    }
#pragma unroll
    for (int j = 0; j < 8; j++) {
      bf16x8 vfB = *(const bf16x8*)(Vl + (j * 16 + q) * 128 + vcolB);
      acc[j] = mfma16(pcB, vfB, acc[j]);
    }
    __builtin_amdgcn_s_setprio(0);

    __builtin_amdgcn_s_barrier();  // V free for overwrite
    if (more) {
#pragma unroll
      for (int i = 0; i < 2; i++)
        gload_lds16(srcV[i] + (size_t)(kt + 1) * 64,
                    lds + 32768 + ((i * 8 + wid) << 10));
    }
  }

  float linv = 1.0f / l;
  float linv_r[4];
#pragma unroll
  for (int r = 0; r < 4; r++)
    linv_r[r] = __shfl(linv, (lane & 48) | (g * 4 + r));
  u16* ab = attn + (size_t)(b * S + q0) * 2048 + h * 128;
#pragma unroll
  for (int j = 0; j < 8; j++)
#pragma unroll
    for (int r = 0; r < 4; r++)
      ab[(size_t)(g * 4 + r) * 2048 + j * 16 + q] = f2bf(acc[j][r] * linv_r[r]);
}

// ---------------- launch ----------------
extern "C" void kernel_launch(void* const* d_in, const int* in_sizes, int n_in,
                              void* d_out, int out_size, void* d_ws, size_t ws_size,
                              hipStream_t stream) {
  (void)in_sizes; (void)n_in; (void)out_size; (void)ws_size;
  const int S = 2048;
  const float* x = (const float*)d_in[0];
  const float* qkv = (const float*)d_in[1];
  const float* wk = (const float*)d_in[2];
  const float* wo = (const float*)d_in[3];
  float* out = (float*)d_out;
  float* k_out = out + (size_t)8388608;
  float* v_out = out + (size_t)16777216;

  char* ws = (char*)d_ws;
  // workspace layout (108.0 MB); attn aliases x_bf, k_bf aliases wcomb
  u16* x_bf  = (u16*)(ws + 0);          // 16.78 MB (later: attn_bf)
  u16* wcomb = (u16*)(ws + 16777216);   // 22.02 MB (5376x2048) (later: k_bf)
  u16* wo_bf = (u16*)(ws + 38797312);   // 8.39 MB
  u16* qvk   = (u16*)(ws + 47185920);   // 44.04 MB (4096x5376)
  u16* vt_bf = (u16*)(ws + 91226112);   // 16.78 MB (B,H,128,S)
  u16* attn_bf = x_bf;
  u16* k_bf = wcomb;

  cast_all<<<23040, 256, 0, stream>>>((const float4*)x, (const float4*)qkv, wk,
                                      (const float4*)wo, x_bf, wcomb, wo_bf);

  // Q+V: cols 0..4095 (one perfect round of 256 blocks)
  gemm256<u16, 256, 256><<<dim3(16, 16), 512, 0, stream>>>(x_bf, wcomb, qvk,
                                                           4096, 5376, 2048);
  // K: cols 4096..5375 (weights rows 4096.., 160 blocks)
  gemm256<u16, 256, 128><<<dim3(10, 16), 512, 0, stream>>>(
      x_bf, wcomb + (size_t)4096 * 2048, qvk + 4096, 4096, 5376, 2048);
  rope_scatter2<<<4096, 256, 0, stream>>>(qvk, k_bf, k_out, S);
  v_scatter<<<8192, 256, 0, stream>>>(qvk, vt_bf, v_out, S);
  flash_attn4<<<512, 512, 0, stream>>>(qvk, k_bf, vt_bf, attn_bf, S);
  gemm256<float, 128, 256><<<dim3(8, 32), 512, 0, stream>>>(attn_bf, wo_bf, out,
                                                            4096, 2048, 2048);
}

// Round 9
// 275.635 us; speedup vs baseline: 2.6026x; 1.0146x over previous
//
#include <hip/hip_runtime.h>
#include <hip/hip_bf16.h>

// Decoupled RoPE MHA on MI355X (gfx950).
// B=2 S=2048 D=2048 H=16 dh=128 nope=64 rope=64
// R9: 32x32 flash, exchange-free P path: A-frags use the lane's OWN P words
// (consistent key permutation in A and B makes the MFMA contraction exact),
// V read as 2x ds_read_b64 at the matching key runs. No permlane/cvtpk asm.

typedef unsigned short u16;
typedef unsigned int u32;
typedef __bf16 bf16x8 __attribute__((ext_vector_type(8)));
typedef float f32x4 __attribute__((ext_vector_type(4)));
typedef float f32x16 __attribute__((ext_vector_type(16)));

__device__ __forceinline__ u16 f2bf(float x) {
  union { __hip_bfloat16 h; u16 u; } c;
  c.h = __float2bfloat16(x);
  return c.u;
}
__device__ __forceinline__ float bf2f(u16 u) {
  union { u32 u; float f; } c;
  c.u = ((u32)u) << 16;
  return c.f;
}
__device__ __forceinline__ u32 pack2(float a, float b) {
  return (u32)f2bf(a) | ((u32)f2bf(b) << 16);
}
__device__ __forceinline__ f32x4 mfma16(bf16x8 a, bf16x8 b, f32x4 c) {
  return __builtin_amdgcn_mfma_f32_16x16x32_bf16(a, b, c, 0, 0, 0);
}
__device__ __forceinline__ f32x16 mfma32(bf16x8 a, bf16x8 b, f32x16 c) {
  return __builtin_amdgcn_mfma_f32_32x32x16_bf16(a, b, c, 0, 0, 0);
}
__device__ __forceinline__ void gload_lds16(const void* g, void* l) {
  __builtin_amdgcn_global_load_lds((__attribute__((address_space(1))) void*)g,
                                   (__attribute__((address_space(3))) void*)l,
                                   16, 0, 0);
}

// ---------------- fused cast kernel ----------------
__global__ __launch_bounds__(256) void cast_all(const float4* __restrict__ x,
                                                const float4* __restrict__ qkv,
                                                const float* __restrict__ wk,
                                                const float4* __restrict__ wo,
                                                u16* __restrict__ x_bf,
                                                u16* __restrict__ wcomb,
                                                u16* __restrict__ wo_bf) {
  int i = blockIdx.x * blockDim.x + threadIdx.x;
  const float4* src;
  u16* dst;
  int j;
  if (i < 2097152) {
    src = x; dst = x_bf; j = i;
  } else if (i < 4194304) {
    src = qkv; dst = wcomb; j = i - 2097152;
  } else if (i < 4849664) {
    j = i - 4194304;  // over 1280x2048/4; rows >=1088 are zero pad
    int r = (j * 4) >> 11;
    u32 lo = 0, hi = 0;
    if (r < 1088) {
      float4 v = ((const float4*)wk)[j];
      lo = pack2(v.x, v.y);
      hi = pack2(v.z, v.w);
    }
    ((uint2*)(wcomb + 8388608))[j] = make_uint2(lo, hi);
    return;
  } else {
    src = wo; dst = wo_bf; j = i - 4849664;
  }
  float4 v = src[j];
  ((uint2*)dst)[j] = make_uint2(pack2(v.x, v.y), pack2(v.z, v.w));
}

// ------------- GEMM BMxBN, BK=64, 4 phases/K-tile, templated (BM,BN) --------
__device__ __forceinline__ void cstore(u16* C, size_t i, float v) { C[i] = f2bf(v); }
__device__ __forceinline__ void cstore(float* C, size_t i, float v) { C[i] = v; }

template <typename CT, int BM, int BN>
__global__ __launch_bounds__(512, 2) void gemm256(const u16* __restrict__ A,
                                                  const u16* __restrict__ W,
                                                  CT* __restrict__ C,
                                                  int M, int N, int K) {
  constexpr int MI = BM / 64;
  constexpr int NI = BN / 128;
  constexpr int AH = BM * 64;
  constexpr int BH = BN * 64;
  constexpr int AL = BM / 128;
  constexpr int BL = BN / 128;
  constexpr int BOFF = 4 * AH;
  __shared__ char lds[BOFF + 4 * BH];
  const int tid = threadIdx.x;
  const int wid = tid >> 6, lane = tid & 63;
  const int lr = lane & 15, lg = lane >> 4;
  const int wr = wid >> 2, wc = wid & 3;
  const int xorv = (lr & 7) << 4;
  const int nwg = gridDim.x * gridDim.y;
  const int lin = blockIdx.y * gridDim.x + blockIdx.x;
  const int swz = (lin & 7) * (nwg >> 3) + (lin >> 3);
  const int m0 = (swz / gridDim.x) * BM;
  const int n0 = (swz % gridDim.x) * BN;
  const int nkt = K >> 6;

  f32x4 acc[2 * MI][2 * NI] = {};
  bf16x8 a[MI][2], b[2 * NI][2];

  const int o0 = tid * 16, o1 = 8192 + tid * 16;
  const int r0 = o0 >> 7, c0 = ((o0 & 127) ^ ((r0 & 7) << 4)) >> 1;
  const int r1 = o1 >> 7, c1 = ((o1 & 127) ^ ((r1 & 7) << 4)) >> 1;
  const u16* gA0[2] = {A + (size_t)(m0 + r0) * K + c0,
                       A + (size_t)(m0 + BM / 2 + r0) * K + c0};
  const u16* gA1[2] = {A + (size_t)(m0 + r1) * K + c1,
                       A + (size_t)(m0 + BM / 2 + r1) * K + c1};
  const u16* gB0[2] = {W + (size_t)(n0 + r0) * K + c0,
                       W + (size_t)(n0 + BN / 2 + r0) * K + c0};
  const u16* gB1[2] = {W + (size_t)(n0 + r1) * K + c1,
                       W + (size_t)(n0 + BN / 2 + r1) * K + c1};

  auto STAGEA = [&](int t, int h) {
    char* d_ = lds + (t & 1) * (2 * AH) + h * AH + wid * 1024;
    gload_lds16(gA0[h] + (size_t)t * 64, d_);
    if constexpr (AL == 2) gload_lds16(gA1[h] + (size_t)t * 64, d_ + 8192);
  };
  auto STAGEB = [&](int t, int h) {
    char* d_ = lds + BOFF + (t & 1) * (2 * BH) + h * BH + wid * 1024;
    gload_lds16(gB0[h] + (size_t)t * 64, d_);
    if constexpr (BL == 2) gload_lds16(gB1[h] + (size_t)t * 64, d_ + 8192);
  };
  auto WAITKEEP = [&]() {
    if constexpr (AL + BL == 4) asm volatile("s_waitcnt vmcnt(4)" ::: "memory");
    else asm volatile("s_waitcnt vmcnt(3)" ::: "memory");
  };

  STAGEA(0, 0); STAGEB(0, 0); STAGEA(0, 1); STAGEB(0, 1);
  if (nkt > 1) { STAGEA(1, 0); STAGEB(1, 0); }
  WAITKEEP();
  __builtin_amdgcn_s_barrier();

  for (int t = 0; t < nkt; ++t) {
    const char* Ab = lds + (t & 1) * (2 * AH);
    const char* Bb = lds + BOFF + (t & 1) * (2 * BH);
    const int arow = wr * (BM / 4), brow = wc * (BN / 8);
    // phase 0
#pragma unroll
    for (int mi = 0; mi < MI; mi++)
#pragma unroll
      for (int ks = 0; ks < 2; ks++)
        a[mi][ks] = *(const bf16x8*)(Ab + (arow + mi * 16 + lr) * 128 + ((lg * 16 + ks * 64) ^ xorv));
#pragma unroll
    for (int ni = 0; ni < NI; ni++)
#pragma unroll
      for (int ks = 0; ks < 2; ks++)
        b[ni][ks] = *(const bf16x8*)(Bb + (brow + ni * 16 + lr) * 128 + ((lg * 16 + ks * 64) ^ xorv));
    if (t + 1 < nkt) STAGEA(t + 1, 1);
    __builtin_amdgcn_s_barrier();
    asm volatile("s_waitcnt lgkmcnt(0)" ::: "memory");
    __builtin_amdgcn_sched_barrier(0);
    __builtin_amdgcn_s_setprio(1);
#pragma unroll
    for (int mi = 0; mi < MI; mi++)
#pragma unroll
      for (int ni = 0; ni < NI; ni++)
#pragma unroll
        for (int ks = 0; ks < 2; ks++)
          acc[mi][ni] = mfma16(a[mi][ks], b[ni][ks], acc[mi][ni]);
    __builtin_amdgcn_s_setprio(0);
    __builtin_amdgcn_s_barrier();
    // phase 1
#pragma unroll
    for (int ni = 0; ni < NI; ni++)
#pragma unroll
      for (int ks = 0; ks < 2; ks++)
        b[NI + ni][ks] = *(const bf16x8*)(Bb + BH + (brow + ni * 16 + lr) * 128 + ((lg * 16 + ks * 64) ^ xorv));
    if (t + 1 < nkt) STAGEB(t + 1, 1);
    __builtin_amdgcn_s_barrier();
    asm volatile("s_waitcnt lgkmcnt(0)" ::: "memory");
    __builtin_amdgcn_sched_barrier(0);
    __builtin_amdgcn_s_setprio(1);
#pragma unroll
    for (int mi = 0; mi < MI; mi++)
#pragma unroll
      for (int ni = 0; ni < NI; ni++)
#pragma unroll
        for (int ks = 0; ks < 2; ks++)
          acc[mi][NI + ni] = mfma16(a[mi][ks], b[NI + ni][ks], acc[mi][NI + ni]);
    __builtin_amdgcn_s_setprio(0);
    __builtin_amdgcn_s_barrier();
    // phase 2
#pragma unroll
    for (int mi = 0; mi < MI; mi++)
#pragma unroll
      for (int ks = 0; ks < 2; ks++)
        a[mi][ks] = *(const bf16x8*)(Ab + AH + (arow + mi * 16 + lr) * 128 + ((lg * 16 + ks * 64) ^ xorv));
    if (t + 2 < nkt) STAGEA(t + 2, 0);
    __builtin_amdgcn_s_barrier();
    asm volatile("s_waitcnt lgkmcnt(0)" ::: "memory");
    __builtin_amdgcn_sched_barrier(0);
    __builtin_amdgcn_s_setprio(1);
#pragma unroll
    for (int mi = 0; mi < MI; mi++)
#pragma unroll
      for (int ni = 0; ni < NI; ni++)
#pragma unroll
        for (int ks = 0; ks < 2; ks++)
          acc[MI + mi][ni] = mfma16(a[mi][ks], b[ni][ks], acc[MI + mi][ni]);
    __builtin_amdgcn_s_setprio(0);
    __builtin_amdgcn_s_barrier();
    // phase 3
    if (t + 2 < nkt) {
      STAGEB(t + 2, 0);
      WAITKEEP();
    } else if (t + 1 < nkt) {
      asm volatile("s_waitcnt vmcnt(0)" ::: "memory");
    }
    __builtin_amdgcn_s_barrier();
    asm volatile("s_waitcnt lgkmcnt(0)" ::: "memory");
    __builtin_amdgcn_sched_barrier(0);
    __builtin_amdgcn_s_setprio(1);
#pragma unroll
    for (int mi = 0; mi < MI; mi++)
#pragma unroll
      for (int ni = 0; ni < NI; ni++)
#pragma unroll
        for (int ks = 0; ks < 2; ks++)
          acc[MI + mi][NI + ni] = mfma16(a[mi][ks], b[NI + ni][ks], acc[MI + mi][NI + ni]);
    __builtin_amdgcn_s_setprio(0);
    __builtin_amdgcn_s_barrier();
  }

#pragma unroll
  for (int Mh = 0; Mh < 2; Mh++)
#pragma unroll
    for (int mi = 0; mi < MI; mi++) {
      int row = m0 + Mh * (BM / 2) + wr * (BM / 4) + mi * 16 + lg * 4;
#pragma unroll
      for (int Nh = 0; Nh < 2; Nh++)
#pragma unroll
        for (int ni = 0; ni < NI; ni++) {
          int col = n0 + Nh * (BN / 2) + wc * (BN / 8) + ni * 16 + lr;
#pragma unroll
          for (int r = 0; r < 4; r++)
            cstore(C, (size_t)(row + r) * N + col, acc[Mh * MI + mi][Nh * NI + ni][r]);
        }
    }
}

// ---------------- RoPE: Q in-place in QVK + K scatter ----------------
__global__ __launch_bounds__(256) void rope_scatter2(u16* __restrict__ QVK,
                                                     u16* __restrict__ kh,
                                                     float* __restrict__ k_out, int S) {
  const int row = blockIdx.x;  // b*S + s
  const int b = row >> 11, s = row & 2047;
  const int tid = threadIdx.x;
  __shared__ float kr[64];
  const float LOG1E4_64 = 0.14391156511f;  // ln(10000)/64
  u16* qrow = QVK + (size_t)row * 5376;
  if (tid < 32) {
    float freq = __expf(-(float)tid * LOG1E4_64);
    float sn, c;
    __sincosf((float)s * freq, &sn, &c);
    float a = bf2f(qrow[5120 + tid]);
    float bb = bf2f(qrow[5152 + tid]);
    kr[tid] = a * c - bb * sn;
    kr[tid + 32] = bb * c + a * sn;
  }
  for (int idx = tid; idx < 512; idx += 256) {
    int h = idx >> 5, jj = idx & 31;
    float freq = __expf(-(float)jj * LOG1E4_64);
    float sn, c;
    __sincosf((float)s * freq, &sn, &c);
    u16* p1 = qrow + h * 128 + 64 + jj;
    u16* p2 = qrow + h * 128 + 96 + jj;
    float x1 = bf2f(*p1), x2 = bf2f(*p2);
    *p1 = f2bf(x1 * c - x2 * sn);
    *p2 = f2bf(x2 * c + x1 * sn);
  }
  __syncthreads();
  for (int idx = tid; idx < 2048; idx += 256) {
    int h = idx >> 7, d = idx & 127;
    float val = (d < 64) ? bf2f(qrow[4096 + h * 64 + d]) : kr[d - 64];
    size_t o = ((size_t)(b * 16 + h) * S + s) * 128 + d;
    kh[o] = f2bf(val);
    k_out[o] = val;
  }
}

// ---------------- V: write v_heads fp32 + transposed Vt (B,H,128,S) ----------
__global__ __launch_bounds__(256) void v_scatter(const u16* __restrict__ QVK,
                                                 u16* __restrict__ vt,
                                                 float* __restrict__ v_out, int S) {
  const int blk = blockIdx.x;
  const int st = blk & 63;
  const int dt = (blk >> 6) & 3;
  const int bh = blk >> 8;
  const int b = bh >> 4, h = bh & 15;
  __shared__ u16 t[32][34];
  const int tx = threadIdx.x & 31, ty = threadIdx.x >> 5;
  const int s0 = st * 32, d0 = dt * 32;
#pragma unroll
  for (int i = 0; i < 4; i++) {
    int sl = ty + 8 * i;
    u16 u = QVK[(size_t)(b * S + s0 + sl) * 5376 + 2048 + h * 128 + d0 + tx];
    t[sl][tx] = u;
    v_out[((size_t)bh * S + s0 + sl) * 128 + d0 + tx] = bf2f(u);
  }
  __syncthreads();
#pragma unroll
  for (int i = 0; i < 4; i++) {
    int dl = ty + 8 * i;
    vt[((size_t)bh * 128 + d0 + dl) * S + s0 + tx] = t[tx][dl];
  }
}

// --------- flash attention v6: 32x32 MFMA, exchange-free P path -------------
// LDS: K0 [0,16K) | K1 [16K,32K) | V [32K,48K) | bcast scratch [48K,48K+512).
// Score C-layout (32x32): col q = lane&31, key = (r&3)+8*(r>>2)+4*(lane>>5).
// Lane's own P words u[kg*8+i] (pairs of keys kg*32+8*(i>>1)+4*hh+2*(i&1)+{0,1})
// are fed DIRECTLY as PV A-frags; V B-frags read the SAME key sets via two
// ds_read_b64 (keys 16ss+4hh+{0..3} and 16ss+8+4hh+{0..3}). A consistent key
// permutation in A and B leaves the MFMA contraction exact -> no cross-lane
// exchange needed at all. Cross-half reduces via __shfl_xor(x,32).
__global__ __launch_bounds__(256) void flash_attn6(const u16* __restrict__ QVK,
                                                   const u16* __restrict__ Kh,
                                                   const u16* __restrict__ Vt,
                                                   u16* __restrict__ attn, int S) {
  __shared__ char lds[49664];
  const int tid = threadIdx.x, wid = tid >> 6, lane = tid & 63;
  const int bh = blockIdx.x & 31;
  const int qb = 15 - (int)(blockIdx.x >> 5);  // longest blocks first
  const int q0w = qb * 128 + wid * 32;
  const int b = bh >> 4, h = bh & 15;
  const int r32 = lane & 31, hh = lane >> 5;
  const u16* Qb = QVK + (size_t)b * S * 5376 + h * 128;
  const u16* Kb = Kh + (size_t)bh * S * 128;
  const u16* Vb = Vt + (size_t)bh * 128 * S;
  const int qg = q0w + r32;
  const int xr = (r32 & 7) << 4;
  char* const Pc = lds + 49152 + wid * 128;

  // stage sources (pre-swizzled), 4 loads per tile for K and for V
  const u16 *srcK[4], *srcV[4];
#pragma unroll
  for (int i = 0; i < 4; i++) {
    int o = i * 4096 + tid * 16;
    int rK = o >> 8, cbK = (o & 255) ^ ((rK & 7) << 4);
    srcK[i] = Kb + rK * 128 + (cbK >> 1);
    int dV = o >> 7, kbV = (o & 127) ^ ((dV & 7) << 4);
    srcV[i] = Vb + (size_t)dV * S + (kbV >> 1);
  }

  bf16x8 qf[8];
#pragma unroll
  for (int f = 0; f < 8; f++)
    qf[f] = *(const bf16x8*)(Qb + (size_t)qg * 5376 + f * 16 + hh * 8);

  f32x16 acc[4] = {};
  float m = -INFINITY, l = 0.f;
  const float sc = 0.08838834764831845f;  // 1/sqrt(128)
  const int ktiles = 2 * qb + 2;

  // prologue: K(0)->buf0, V(0)
#pragma unroll
  for (int i = 0; i < 4; i++) {
    char* ld = lds + i * 4096 + wid * 1024;
    gload_lds16(srcK[i], ld);
    gload_lds16(srcV[i], ld + 32768);
  }
  asm volatile("s_waitcnt vmcnt(0)" ::: "memory");
  __builtin_amdgcn_s_barrier();

  for (int kt = 0; kt < ktiles; ++kt) {
    const char* Kt = lds + (kt & 1) * 16384;
    const char* Vl = lds + 32768;
    const bool more = (kt + 1 < ktiles);
    if (more) {
#pragma unroll
      for (int i = 0; i < 4; i++)
        gload_lds16(srcK[i] + (size_t)(kt + 1) * 8192,
                    lds + (((kt & 1) ^ 1) << 14) + i * 4096 + wid * 1024);
      asm volatile("s_waitcnt vmcnt(8)" ::: "memory");
    } else {
      asm volatile("s_waitcnt vmcnt(4)" ::: "memory");
    }
    __builtin_amdgcn_s_barrier();

    const int kbg = kt * 64;
    const bool active = (kbg <= q0w + 31);  // wave-uniform
    u32 u[16];
    if (active) {
      f32x16 s[2] = {};
      __builtin_amdgcn_s_setprio(1);
#pragma unroll
      for (int kg = 0; kg < 2; kg++) {
        const char* Kq = Kt + (kg * 32 + r32) * 256;
#pragma unroll
        for (int f = 0; f < 8; f++) {
          bf16x8 kf = *(const bf16x8*)(Kq + ((f * 32 + hh * 16) ^ xr));
          s[kg] = mfma32(kf, qf[f], s[kg]);
        }
      }
      __builtin_amdgcn_s_setprio(0);
      const bool maskt = (kbg + 63 > q0w);
      if (maskt) {
#pragma unroll
        for (int kg = 0; kg < 2; kg++)
#pragma unroll
          for (int r = 0; r < 16; r++)
            if (kbg + kg * 32 + (r & 3) + 8 * (r >> 2) + 4 * hh > qg)
              s[kg][r] = -1e30f;
      }
      float tm = s[0][0];
#pragma unroll
      for (int r = 1; r < 16; r++) tm = fmaxf(tm, s[0][r]);
#pragma unroll
      for (int r = 0; r < 16; r++) tm = fmaxf(tm, s[1][r]);
      tm = fmaxf(tm, __shfl_xor(tm, 32));
      // defer-max: rescale only when raw max grew by > 64 (5.7 nats scaled)
      if (!__all(tm <= m + 64.0f)) {
        float mnew = fmaxf(m, tm);
        float corr = __expf((m - mnew) * sc);
        m = mnew;
        l *= corr;
        if (lane < 32) *(float*)(Pc + r32 * 4) = corr;
        asm volatile("s_waitcnt lgkmcnt(0)" ::: "memory");
        __builtin_amdgcn_sched_barrier(0);
        f32x4 c0 = *(const f32x4*)(Pc + (4 * hh) * 4);
        f32x4 c1 = *(const f32x4*)(Pc + (8 + 4 * hh) * 4);
        f32x4 c2 = *(const f32x4*)(Pc + (16 + 4 * hh) * 4);
        f32x4 c3 = *(const f32x4*)(Pc + (24 + 4 * hh) * 4);
#pragma unroll
        for (int dg = 0; dg < 4; dg++)
#pragma unroll
          for (int r = 0; r < 16; r++) {
            float cr = (r >> 2) == 0 ? c0[r & 3]
                     : (r >> 2) == 1 ? c1[r & 3]
                     : (r >> 2) == 2 ? c2[r & 3] : c3[r & 3];
            acc[dg][r] *= cr;
          }
      }
      const float nms = -m * sc;
      float ts = 0.f;
#pragma unroll
      for (int kg = 0; kg < 2; kg++)
#pragma unroll
        for (int r = 0; r < 16; r++) {
          float pv = __expf(fmaf(s[kg][r], sc, nms));
          s[kg][r] = pv;
          ts += pv;
        }
      ts += __shfl_xor(ts, 32);
      l += ts;
      // pack P pairs (keys kg*32 + 8*(i>>1) + 4*hh + 2*(i&1) + {0,1})
#pragma unroll
      for (int kg = 0; kg < 2; kg++)
#pragma unroll
        for (int i = 0; i < 8; i++)
          u[kg * 8 + i] = pack2(s[kg][2 * i], s[kg][2 * i + 1]);
    }

    if (more) asm volatile("s_waitcnt vmcnt(4)" ::: "memory");
    else      asm volatile("s_waitcnt vmcnt(0)" ::: "memory");
    __builtin_amdgcn_s_barrier();

    if (active) {
      __builtin_amdgcn_s_setprio(1);
#pragma unroll
      for (int dg = 0; dg < 4; dg++) {
        const char* Vq = Vl + (dg * 32 + r32) * 128;
#pragma unroll
        for (int ss = 0; ss < 4; ss++) {
          // B-frag keys must match A-frag slot keys: 16ss+4hh+{0..3} then
          // 16ss+8+4hh+{0..3}  (two 8-byte LDS reads)
          uint2 vlo = *(const uint2*)(Vq + ((ss * 32 + 8 * hh) ^ xr));
          uint2 vhi = *(const uint2*)(Vq + ((ss * 32 + 16 + 8 * hh) ^ xr));
          union { u32 w[4]; bf16x8 v; } vb, pa;
          vb.w[0] = vlo.x; vb.w[1] = vlo.y; vb.w[2] = vhi.x; vb.w[3] = vhi.y;
          pa.w[0] = u[ss * 4 + 0];
          pa.w[1] = u[ss * 4 + 1];
          pa.w[2] = u[ss * 4 + 2];
          pa.w[3] = u[ss * 4 + 3];
          acc[dg] = mfma32(pa.v, vb.v, acc[dg]);
        }
      }
      __builtin_amdgcn_s_setprio(0);
    }
    __builtin_amdgcn_s_barrier();  // V free for overwrite
    if (more) {
#pragma unroll
      for (int i = 0; i < 4; i++)
        gload_lds16(srcV[i] + (size_t)(kt + 1) * 64,
                    lds + 32768 + i * 4096 + wid * 1024);
    }
  }

  float linv = 1.0f / l;
  if (lane < 32) *(float*)(Pc + r32 * 4) = linv;
  asm volatile("s_waitcnt lgkmcnt(0)" ::: "memory");
  __builtin_amdgcn_sched_barrier(0);
  f32x4 l0 = *(const f32x4*)(Pc + (4 * hh) * 4);
  f32x4 l1 = *(const f32x4*)(Pc + (8 + 4 * hh) * 4);
  f32x4 l2 = *(const f32x4*)(Pc + (16 + 4 * hh) * 4);
  f32x4 l3 = *(const f32x4*)(Pc + (24 + 4 * hh) * 4);
  u16* ab = attn + (size_t)(b * S + q0w) * 2048 + h * 128;
#pragma unroll
  for (int dg = 0; dg < 4; dg++)
#pragma unroll
    for (int r = 0; r < 16; r++) {
      int rowl = (r & 3) + 8 * (r >> 2) + 4 * hh;
      float li = (r >> 2) == 0 ? l0[r & 3]
               : (r >> 2) == 1 ? l1[r & 3]
               : (r >> 2) == 2 ? l2[r & 3] : l3[r & 3];
      ab[(size_t)rowl * 2048 + dg * 32 + r32] = f2bf(acc[dg][r] * li);
    }
}

// ---------------- launch ----------------
extern "C" void kernel_launch(void* const* d_in, const int* in_sizes, int n_in,
                              void* d_out, int out_size, void* d_ws, size_t ws_size,
                              hipStream_t stream) {
  (void)in_sizes; (void)n_in; (void)out_size; (void)ws_size;
  const int S = 2048;
  const float* x = (const float*)d_in[0];
  const float* qkv = (const float*)d_in[1];
  const float* wk = (const float*)d_in[2];
  const float* wo = (const float*)d_in[3];
  float* out = (float*)d_out;
  float* k_out = out + (size_t)8388608;
  float* v_out = out + (size_t)16777216;

  char* ws = (char*)d_ws;
  // workspace layout (108.0 MB); attn aliases x_bf, k_bf aliases wcomb
  u16* x_bf  = (u16*)(ws + 0);          // 16.78 MB (later: attn_bf)
  u16* wcomb = (u16*)(ws + 16777216);   // 22.02 MB (5376x2048) (later: k_bf)
  u16* wo_bf = (u16*)(ws + 38797312);   // 8.39 MB
  u16* qvk   = (u16*)(ws + 47185920);   // 44.04 MB (4096x5376)
  u16* vt_bf = (u16*)(ws + 91226112);   // 16.78 MB (B,H,128,S)
  u16* attn_bf = x_bf;
  u16* k_bf = wcomb;

  cast_all<<<23040, 256, 0, stream>>>((const float4*)x, (const float4*)qkv, wk,
                                      (const float4*)wo, x_bf, wcomb, wo_bf);

  // Q+V: cols 0..4095 (one perfect round of 256 blocks)
  gemm256<u16, 256, 256><<<dim3(16, 16), 512, 0, stream>>>(x_bf, wcomb, qvk,
                                                           4096, 5376, 2048);
  // K: cols 4096..5375 (weights rows 4096.., 160 blocks)
  gemm256<u16, 256, 128><<<dim3(10, 16), 512, 0, stream>>>(
      x_bf, wcomb + (size_t)4096 * 2048, qvk + 4096, 4096, 5376, 2048);
  rope_scatter2<<<4096, 256, 0, stream>>>(qvk, k_bf, k_out, S);
  v_scatter<<<8192, 256, 0, stream>>>(qvk, vt_bf, v_out, S);
  flash_attn6<<<512, 256, 0, stream>>>(qvk, k_bf, vt_bf, attn_bf, S);
  gemm256<float, 128, 256><<<dim3(8, 32), 512, 0, stream>>>(attn_bf, wo_bf, out,
                                                            4096, 2048, 2048);
}